// Round 2
// baseline (23070.216 us; speedup 1.0000x reference)
//
#include <hip/hip_runtime.h>

typedef __bf16 bf16x8 __attribute__((ext_vector_type(8)));
typedef float f32x4 __attribute__((ext_vector_type(4)));

#define DEV static __device__ __forceinline__

DEV float bf2f(unsigned short u){ union { unsigned u; float f; } x; x.u = ((unsigned)u) << 16; return x.f; }
DEV unsigned short f2bf(float f){
  union { float f; unsigned u; } x; x.f = f;
  unsigned r = x.u + 0x7fffu + ((x.u >> 16) & 1u);
  return (unsigned short)(r >> 16);
}
DEV unsigned pack2(unsigned short lo, unsigned short hi){ return (unsigned)lo | ((unsigned)hi << 16); }
DEV float sigm(float x){ return 1.0f / (1.0f + expf(-x)); }
DEV float tanh_fast(float x){ float e = __expf(2.0f * x); return 1.0f - 2.0f / (e + 1.0f); }

// ---- device-scope grid barrier (counter zeroed via memset before launch) ----
DEV void gridbar(unsigned* bar, unsigned target){
  __syncthreads();
  if (threadIdx.x == 0){
    __builtin_amdgcn_fence(__ATOMIC_RELEASE, "agent");
    __hip_atomic_fetch_add(bar, 1u, __ATOMIC_RELAXED, __HIP_MEMORY_SCOPE_AGENT);
    while (__hip_atomic_load(bar, __ATOMIC_RELAXED, __HIP_MEMORY_SCOPE_AGENT) < target)
      __builtin_amdgcn_s_sleep(1);
    __builtin_amdgcn_fence(__ATOMIC_ACQUIRE, "agent");
  }
  __syncthreads();
}

// ---------------- f32 -> bf16 convert (n4 = count/4) ----------------
__global__ void k_f2bf(const float4* __restrict__ in, uint2* __restrict__ out, long n4){
  long stride = (long)gridDim.x * blockDim.x;
  for (long i = (long)blockIdx.x * blockDim.x + threadIdx.x; i < n4; i += stride){
    float4 v = in[i];
    uint2 o; o.x = pack2(f2bf(v.x), f2bf(v.y)); o.y = pack2(f2bf(v.z), f2bf(v.w));
    out[i] = o;
  }
}

// Ws_att [a][k] f32 -> packed bf16 pairs along k: out[kp*512 + a] = (Ws[a][2kp], Ws[a][2kp+1])
__global__ void k_wst(const float* __restrict__ in, unsigned* __restrict__ out){
  int i = blockIdx.x * 256 + threadIdx.x;   // 131072 total: kp = i>>9, a = i&511
  int kp = i >> 9, a = i & 511;
  const float* r = in + (size_t)a * 512 + 2 * kp;
  out[i] = pack2(f2bf(r[0]), f2bf(r[1]));
}

__global__ void k_bias3(const float* a0, const float* b0, float* o0,
                        const float* a1, const float* b1, float* o1,
                        const float* a2, const float* b2, float* o2){
  int i = blockIdx.x * 256 + threadIdx.x;   // 2048
  o0[i] = a0[i] + b0[i];
  o1[i] = a1[i] + b1[i];
  o2[i] = a2[i] + b2[i];
}

// embedding gather -> bf16 rows. row r = pos*16 + b ; token = tok[b*128 + pos]
__global__ void k_embed(const int* __restrict__ tok, const float* __restrict__ table,
                        unsigned short* __restrict__ out){
  int r = blockIdx.x;
  int b = r & 15, pos = r >> 4;
  int idx = tok[b * 128 + pos];
  float4 v = ((const float4*)(table + (size_t)idx * 512))[threadIdx.x];  // 128 threads
  uint2 o; o.x = pack2(f2bf(v.x), f2bf(v.y)); o.y = pack2(f2bf(v.z), f2bf(v.w));
  ((uint2*)(out + (size_t)r * 512))[threadIdx.x] = o;
}

// ---------------- bf16 MFMA GEMM: C[M,N] = A[M,K] * B[N,K]^T (+bias) ----------------
template<int MODE>
__global__ __launch_bounds__(256)
void gemm_bt(const unsigned short* __restrict__ A, int lda,
             const unsigned short* __restrict__ B, int ldb,
             const float* __restrict__ bias,
             float* __restrict__ C, int ldc, int K, int mvalid)
{
  __shared__ __align__(16) unsigned short As[128 * 64];
  __shared__ __align__(16) unsigned short Bs[128 * 64];
  const int tid  = threadIdx.x;
  const int lane = tid & 63, wid = tid >> 6;
  const int wm = (wid >> 1) * 64, wn = (wid & 1) * 64;
  const unsigned short* Ab = A + (size_t)blockIdx.y * 128 * lda;
  const unsigned short* Bb = B + (size_t)blockIdx.x * 128 * ldb;

  f32x4 acc[4][4] = {};
  bf16x8 ga[4], gb[4];

  #pragma unroll
  for (int r = 0; r < 4; r++){
    int c = tid + r * 256;
    ga[r] = *(const bf16x8*)(Ab + (size_t)(c >> 3) * lda + (c & 7) * 8);
    gb[r] = *(const bf16x8*)(Bb + (size_t)(c >> 3) * ldb + (c & 7) * 8);
  }
  const int nt = K >> 6;
  for (int t = 0; t < nt; t++){
    #pragma unroll
    for (int r = 0; r < 4; r++){
      int c = tid + r * 256;
      int slot = ((c >> 3) * 8 + ((c & 7) ^ ((c >> 3) & 7))) * 8;
      *(bf16x8*)(As + slot) = ga[r];
      *(bf16x8*)(Bs + slot) = gb[r];
    }
    __syncthreads();
    if (t + 1 < nt){
      int k0 = (t + 1) * 64;
      #pragma unroll
      for (int r = 0; r < 4; r++){
        int c = tid + r * 256;
        ga[r] = *(const bf16x8*)(Ab + (size_t)(c >> 3) * lda + k0 + (c & 7) * 8);
        gb[r] = *(const bf16x8*)(Bb + (size_t)(c >> 3) * ldb + k0 + (c & 7) * 8);
      }
    }
    #pragma unroll
    for (int kk = 0; kk < 2; kk++){
      bf16x8 av[4], bv[4];
      #pragma unroll
      for (int i = 0; i < 4; i++){
        int ra = wm + i * 16 + (lane & 15);
        int ua = (kk * 4 + (lane >> 4)) ^ (ra & 7);
        av[i] = *(const bf16x8*)(As + (ra * 8 + ua) * 8);
        int rb = wn + i * 16 + (lane & 15);
        int ub = (kk * 4 + (lane >> 4)) ^ (rb & 7);
        bv[i] = *(const bf16x8*)(Bs + (rb * 8 + ub) * 8);
      }
      #pragma unroll
      for (int i = 0; i < 4; i++)
        #pragma unroll
        for (int j = 0; j < 4; j++)
          acc[i][j] = __builtin_amdgcn_mfma_f32_16x16x32_bf16(av[i], bv[j], acc[i][j], 0, 0, 0);
    }
    if (t + 1 < nt) __syncthreads();
  }

  const int cb = lane & 15, rb4 = (lane >> 4) * 4;
  #pragma unroll
  for (int i = 0; i < 4; i++){
    #pragma unroll
    for (int j = 0; j < 4; j++){
      #pragma unroll
      for (int r = 0; r < 4; r++){
        int row = blockIdx.y * 128 + wm + i * 16 + rb4 + r;
        int col = blockIdx.x * 128 + wn + j * 16 + cb;
        float v = acc[i][j][r];
        if (bias) v += bias[col];
        if (MODE == 0){
          C[(size_t)row * ldc + col] = v;
        } else {
          if (row < mvalid){
            int tt = row >> 4, b = row & 15;
            C[((size_t)b * 127 + tt) * 32000 + col] = v;
          }
        }
      }
    }
  }
}

// ---------------- persistent encoder: all 128 LSTM steps, both directions ----------------
// grid 64 x 256 thr. dir = bx>>5, chunk = bx&31 (16 j per block). b = tid&15, jj = tid>>4.
__global__ __launch_bounds__(256)
void enc_persist(const float* __restrict__ gin_f, const float* __restrict__ gin_b,
                 const float* __restrict__ Whh_f, const float* __restrict__ Whh_b,
                 float* __restrict__ h_enc,   /* [2 parity][2 dir][16][512] */
                 float* __restrict__ enc_out, /* [16][128][1024] f32 */
                 unsigned short* __restrict__ enc_out_bf,
                 unsigned* __restrict__ bar)
{
  __shared__ float hl[512 * 17];
  const int bx = blockIdx.x;
  const int dir = bx >> 5, chunk = bx & 31;
  const int tid = threadIdx.x;
  const int b = tid & 15, jj = tid >> 4;
  const int j = chunk * 16 + jj;
  const float* gin = dir ? gin_b : gin_f;
  const float* Whh = dir ? Whh_b : Whh_f;
  const float* w0 = Whh + (size_t)j * 512;
  const float* w1 = Whh + (size_t)(512 + j) * 512;
  const float* w2 = Whh + (size_t)(1024 + j) * 512;
  const float* w3 = Whh + (size_t)(1536 + j) * 512;
  float cv = 0.0f;
  unsigned tgt = 0;

  for (int t = 0; t < 128; t++){
    const int p = t & 1;
    const int s_in = dir ? (127 - t) : t;
    const float* hprev = h_enc + (size_t)(p * 2 + dir) * 8192;
    float* hnext       = h_enc + (size_t)(((p ^ 1) * 2) + dir) * 8192;

    for (int e4 = tid; e4 < 2048; e4 += 256){
      int bb = e4 >> 7, k4 = (e4 & 127) * 4;
      float4 v = *(const float4*)(hprev + bb * 512 + k4);
      hl[(k4 + 0) * 17 + bb] = v.x;
      hl[(k4 + 1) * 17 + bb] = v.y;
      hl[(k4 + 2) * 17 + bb] = v.z;
      hl[(k4 + 3) * 17 + bb] = v.w;
    }
    __syncthreads();

    const float* grow = gin + (size_t)(s_in * 16 + b) * 2048;
    float a0 = grow[j], a1 = grow[512 + j], a2 = grow[1024 + j], a3 = grow[1536 + j];
    for (int k = 0; k < 512; k += 4){
      float4 x0 = *(const float4*)(w0 + k);
      float4 x1 = *(const float4*)(w1 + k);
      float4 x2 = *(const float4*)(w2 + k);
      float4 x3 = *(const float4*)(w3 + k);
      float h0 = hl[(k + 0) * 17 + b], h1 = hl[(k + 1) * 17 + b];
      float h2 = hl[(k + 2) * 17 + b], h3 = hl[(k + 3) * 17 + b];
      a0 += x0.x * h0 + x0.y * h1 + x0.z * h2 + x0.w * h3;
      a1 += x1.x * h0 + x1.y * h1 + x1.z * h2 + x1.w * h3;
      a2 += x2.x * h0 + x2.y * h1 + x2.z * h2 + x2.w * h3;
      a3 += x3.x * h0 + x3.y * h1 + x3.z * h2 + x3.w * h3;
    }
    float ig = sigm(a0), fg = sigm(a1), gg = tanhf(a2), og = sigm(a3);
    float cn = fg * cv + ig * gg;
    float hv = og * tanhf(cn);
    cv = cn;
    hnext[b * 512 + j] = hv;
    size_t eo = ((size_t)b * 128 + s_in) * 1024 + dir * 512 + j;
    enc_out[eo] = hv;
    enc_out_bf[eo] = f2bf(hv);

    tgt += 64;
    gridbar(bar, tgt);
  }
}

// ---------------- h0/c0 ----------------
__global__ __launch_bounds__(512)
void k_h0c0(const float* __restrict__ h_enc, const float* __restrict__ Wbh, const float* __restrict__ bbh,
            const float* __restrict__ Wbc, const float* __restrict__ bbc,
            float* __restrict__ h_dec, float* __restrict__ c_dec)
{
  __shared__ float hc[1024];
  int b = blockIdx.x >> 1, which = blockIdx.x & 1;
  int tid = threadIdx.x;
  hc[tid]       = h_enc[b * 512 + tid];          // final forward h (parity 0, dir 0)
  hc[512 + tid] = h_enc[8192 + b * 512 + tid];   // final backward h (parity 0, dir 1)
  __syncthreads();
  const float* W = which ? Wbc : Wbh;
  float acc = (which ? bbc : bbh)[tid];
  const float* wr = W + (size_t)tid * 1024;
  for (int k = 0; k < 1024; k += 4){
    float4 w = *(const float4*)(wr + k);
    acc += w.x * hc[k] + w.y * hc[k + 1] + w.z * hc[k + 2] + w.w * hc[k + 3];
  }
  float v = tanhf(acc);
  if (which) c_dec[b * 512 + tid] = v;
  else       h_dec[b * 512 + tid] = v;
}

// ---------------- persistent decoder: all 127 steps ----------------
// grid 64 x 512 thr. Phase ABC (attention) on blocks 0..15; phase D (gates) on all 64.
// Phase D: db = tid&15, idx = tid>>4 (0..31): g = idx>>3, jo = idx&7, j0 = bx*8.
__global__ __launch_bounds__(512)
void dec_persist(float* __restrict__ h_dec, const float* __restrict__ c_dec0,
                 const unsigned* __restrict__ wst_pk, const float* __restrict__ v_att,
                 const float* __restrict__ enc_proj, const float* __restrict__ enc_out,
                 const int* __restrict__ src_lens,
                 const float* __restrict__ gin_d,
                 const float* __restrict__ Wih_d, const float* __restrict__ Whh_d,
                 float* __restrict__ ctx, unsigned short* __restrict__ hctx,
                 unsigned* __restrict__ bar)
{
  __shared__ float hl2[512];
  __shared__ float hs2[512];
  __shared__ float vl[512];
  __shared__ float att[128];
  __shared__ float xl[128 * 17];
  __shared__ float gl[4][8][16];

  const int bx = blockIdx.x;
  const int tid = threadIdx.x;
  // phase D mapping
  const int db = tid & 15, idx = tid >> 4;
  const int g = idx >> 3, jo = idx & 7;
  const int j0 = bx * 8;
  const int nD = g * 512 + j0 + jo;
  // registerized cell state: threads idx<8 own (b=db, j=j0+idx)
  float creg = 0.0f;
  if (idx < 8) creg = c_dec0[db * 512 + j0 + idx];

  if (bx < 16) vl[tid] = v_att[tid];   // tid covers 0..511
  unsigned tgt = 0;

  for (int t = 0; t < 127; t++){
    const int p = t & 1;
    const float* h = h_dec + (size_t)p * 8192;
    float* hn      = h_dec + (size_t)(p ^ 1) * 8192;

    if (bx < 16){
      const int b = bx;
      hl2[tid] = h[b * 512 + tid];
      __syncthreads();
      // hs[j] = sum_k h[k] * Ws_att[j][k]  (packed bf16 pairs along k)
      {
        float s0 = 0.f, s1 = 0.f;
        for (int kp = 0; kp < 256; kp++){
          unsigned u = wst_pk[kp * 512 + tid];
          s0 += hl2[2 * kp]     * bf2f((unsigned short)(u & 0xffffu));
          s1 += hl2[2 * kp + 1] * bf2f((unsigned short)(u >> 16));
        }
        hs2[tid] = s0 + s1;
      }
      __syncthreads();
      // scores: 4 lanes per s
      {
        const int s = tid >> 2, part = tid & 3;
        const float* ep  = enc_proj + ((size_t)b * 128 + s) * 512 + part * 128;
        const float* hsp = hs2 + part * 128;
        const float* vp  = vl  + part * 128;
        float sa = 0.f, sb = 0.f;
        for (int a = 0; a < 128; a += 4){
          float4 e4 = *(const float4*)(ep + a);
          float t0 = tanh_fast(e4.x + hsp[a + 0]);
          float t1 = tanh_fast(e4.y + hsp[a + 1]);
          float t2 = tanh_fast(e4.z + hsp[a + 2]);
          float t3 = tanh_fast(e4.w + hsp[a + 3]);
          sa += vp[a + 0] * t0 + vp[a + 1] * t1;
          sb += vp[a + 2] * t2 + vp[a + 3] * t3;
        }
        float sv = sa + sb;
        sv += __shfl_xor(sv, 1);
        sv += __shfl_xor(sv, 2);
        if (part == 0) att[s] = sv;
      }
      __syncthreads();
      if (tid < 64){
        int slen = src_lens[b];
        float x0 = (tid < slen)      ? att[tid]      : -1e9f;
        float x1 = (tid + 64 < slen) ? att[tid + 64] : -1e9f;
        float m = fmaxf(x0, x1);
        #pragma unroll
        for (int o = 32; o; o >>= 1) m = fmaxf(m, __shfl_xor(m, o));
        float e0 = expf(x0 - m), e1 = expf(x1 - m);
        float ssum = e0 + e1;
        #pragma unroll
        for (int o = 32; o; o >>= 1) ssum += __shfl_xor(ssum, o);
        float inv = 1.0f / ssum;
        att[tid] = e0 * inv; att[tid + 64] = e1 * inv;
      }
      __syncthreads();
      // ctx: thread -> cols 2*tid, 2*tid+1 of 1024
      {
        const float* eo = enc_out + (size_t)b * 131072 + 2 * tid;
        float c0 = 0.f, c1 = 0.f, d0 = 0.f, d1 = 0.f;
        for (int s2 = 0; s2 < 128; s2 += 2){
          float aa = att[s2], ab = att[s2 + 1];
          float2 e0 = *(const float2*)(eo + (size_t)s2 * 1024);
          float2 e1 = *(const float2*)(eo + (size_t)s2 * 1024 + 1024);
          c0 += aa * e0.x; c1 += aa * e0.y;
          d0 += ab * e1.x; d1 += ab * e1.y;
        }
        float rx = c0 + d0, ry = c1 + d1;
        float2 rv; rv.x = rx; rv.y = ry;
        *(float2*)(ctx + b * 1024 + 2 * tid) = rv;
        size_t row = (size_t)t * 16 + b;
        *(unsigned*)(hctx + row * 1536 + 512 + 2 * tid) = pack2(f2bf(rx), f2bf(ry));
      }
    }

    tgt += 64;
    gridbar(bar, tgt);

    // ---- phase D: gates (all 64 blocks) ----
    {
      float ac0 = 0.f, ac1 = 0.f, ac2 = 0.f, ac3 = 0.f;
      for (int ch = 0; ch < 12; ch++){
        #pragma unroll
        for (int e = tid; e < 2048; e += 512){
          int bb = e >> 7, kk = e & 127;
          int kg = ch * 128 + kk;
          xl[kk * 17 + bb] = (kg < 1024) ? ctx[bb * 1024 + kg] : h[bb * 512 + (kg - 1024)];
        }
        __syncthreads();
        const float* W = (ch < 8) ? (Wih_d + (size_t)nD * 1536 + 512 + ch * 128)
                                  : (Whh_d + (size_t)nD * 512 + (ch - 8) * 128);
        for (int kk = 0; kk < 128; kk += 4){
          float4 w = *(const float4*)(W + kk);
          ac0 += w.x * xl[(kk + 0) * 17 + db];
          ac1 += w.y * xl[(kk + 1) * 17 + db];
          ac2 += w.z * xl[(kk + 2) * 17 + db];
          ac3 += w.w * xl[(kk + 3) * 17 + db];
        }
        __syncthreads();
      }
      float acc = gin_d[((size_t)t * 16 + db) * 2048 + nD] + ((ac0 + ac1) + (ac2 + ac3));
      gl[g][jo][db] = acc;
      __syncthreads();
      if (idx < 8){
        int jc = j0 + idx;
        float ig = sigm(gl[0][idx][db]);
        float fg = sigm(gl[1][idx][db]);
        float gg = tanhf(gl[2][idx][db]);
        float og = sigm(gl[3][idx][db]);
        float cn = fg * creg + ig * gg;
        float hv = og * tanhf(cn);
        creg = cn;
        hn[db * 512 + jc] = hv;
        hctx[((size_t)t * 16 + db) * 1536 + jc] = f2bf(hv);
      }
    }

    tgt += 64;
    gridbar(bar, tgt);
  }
}

extern "C" void kernel_launch(void* const* d_in, const int* in_sizes, int n_in,
                              void* d_out, int out_size, void* d_ws, size_t ws_size,
                              hipStream_t stream)
{
  const int*   src       = (const int*)d_in[0];
  const int*   src_lens  = (const int*)d_in[1];
  const int*   tgt       = (const int*)d_in[2];
  const float* enc_embed = (const float*)d_in[3];
  const float* Wih_f = (const float*)d_in[4];
  const float* Whh_f = (const float*)d_in[5];
  const float* bih_f = (const float*)d_in[6];
  const float* bhh_f = (const float*)d_in[7];
  const float* Wih_b = (const float*)d_in[8];
  const float* Whh_b = (const float*)d_in[9];
  const float* bih_b = (const float*)d_in[10];
  const float* bhh_b = (const float*)d_in[11];
  const float* Wbh = (const float*)d_in[12];
  const float* bbh = (const float*)d_in[13];
  const float* Wbc = (const float*)d_in[14];
  const float* bbc = (const float*)d_in[15];
  const float* Wh_att = (const float*)d_in[16];
  const float* Ws_att = (const float*)d_in[17];
  const float* v_att  = (const float*)d_in[18];
  const float* dec_embed = (const float*)d_in[19];
  const float* Wih_d = (const float*)d_in[20];
  const float* Whh_d = (const float*)d_in[21];
  const float* bih_d = (const float*)d_in[22];
  const float* bhh_d = (const float*)d_in[23];
  const float* Wfc = (const float*)d_in[24];
  const float* bfc = (const float*)d_in[25];
  float* out = (float*)d_out;

  char* base = (char*)d_ws;
  size_t off = 0;
  auto take = [&](size_t bytes) -> char* {
    char* p = base + off;
    off += (bytes + 255) & ~(size_t)255;
    return p;
  };
  unsigned short* wfc_bf    = (unsigned short*)take((size_t)32000 * 1536 * 2);
  unsigned short* emb_e     = (unsigned short*)take((size_t)2048 * 512 * 2);
  unsigned short* emb_d     = (unsigned short*)take((size_t)2048 * 512 * 2);
  unsigned short* wihf_bf   = (unsigned short*)take((size_t)2048 * 512 * 2);
  unsigned short* wihb_bf   = (unsigned short*)take((size_t)2048 * 512 * 2);
  unsigned short* wihd_bf   = (unsigned short*)take((size_t)2048 * 1536 * 2);
  unsigned short* whatt_bf  = (unsigned short*)take((size_t)512 * 1024 * 2);
  unsigned*       wst_pk    = (unsigned*)take((size_t)256 * 512 * 4);
  float* gin_f    = (float*)take((size_t)2048 * 2048 * 4);
  float* gin_b    = (float*)take((size_t)2048 * 2048 * 4);
  float* gin_d    = (float*)take((size_t)2048 * 2048 * 4);
  float* enc_out  = (float*)take((size_t)16 * 128 * 1024 * 4);
  unsigned short* enc_out_bf = (unsigned short*)take((size_t)2048 * 1024 * 2);
  float* enc_proj = (float*)take((size_t)2048 * 512 * 4);
  unsigned short* hctx = (unsigned short*)take((size_t)2048 * 1536 * 2);
  float* h_enc = (float*)take((size_t)2 * 2 * 16 * 512 * 4);
  float* h_dec = (float*)take((size_t)2 * 16 * 512 * 4);
  float* c_dec = (float*)take((size_t)16 * 512 * 4);
  float* ctxb  = (float*)take((size_t)16 * 1024 * 4);
  float* bias_f = (float*)take(2048 * 4);
  float* bias_b = (float*)take(2048 * 4);
  float* bias_d = (float*)take(2048 * 4);
  unsigned* barbuf = (unsigned*)take(256);
  unsigned* bar_enc = barbuf;
  unsigned* bar_dec = barbuf + 32;

  // zero: state region (h_enc..ctxb), padded dec-embedding rows, padded hctx rows, barriers
  hipMemsetAsync(h_enc, 0, (size_t)((char*)ctxb - (char*)h_enc) + 16 * 1024 * 4, stream);
  hipMemsetAsync(emb_d, 0, (size_t)2048 * 512 * 2, stream);
  hipMemsetAsync(hctx, 0, (size_t)2048 * 1536 * 2, stream);
  hipMemsetAsync(barbuf, 0, 256, stream);

  // weight conversions
  k_f2bf<<<4096, 256, 0, stream>>>((const float4*)Wfc,   (uint2*)wfc_bf,   (long)32000 * 1536 / 4);
  k_f2bf<<<512,  256, 0, stream>>>((const float4*)Wih_f, (uint2*)wihf_bf,  (long)2048 * 512 / 4);
  k_f2bf<<<512,  256, 0, stream>>>((const float4*)Wih_b, (uint2*)wihb_bf,  (long)2048 * 512 / 4);
  k_f2bf<<<1024, 256, 0, stream>>>((const float4*)Wih_d, (uint2*)wihd_bf,  (long)2048 * 1536 / 4);
  k_f2bf<<<512,  256, 0, stream>>>((const float4*)Wh_att,(uint2*)whatt_bf, (long)512 * 1024 / 4);
  k_wst<<<512, 256, 0, stream>>>(Ws_att, wst_pk);
  k_bias3<<<8, 256, 0, stream>>>(bih_f, bhh_f, bias_f, bih_b, bhh_b, bias_b, bih_d, bhh_d, bias_d);

  // embeddings (bf16), rows r = pos*16 + b
  k_embed<<<2048, 128, 0, stream>>>(src, enc_embed, emb_e);
  k_embed<<<2032, 128, 0, stream>>>(tgt, dec_embed, emb_d);

  // input-side gate GEMMs (hoisted out of the scans)
  gemm_bt<0><<<dim3(16, 16), 256, 0, stream>>>(emb_e, 512, wihf_bf, 512,  bias_f, gin_f, 2048, 512, 4096);
  gemm_bt<0><<<dim3(16, 16), 256, 0, stream>>>(emb_e, 512, wihb_bf, 512,  bias_b, gin_b, 2048, 512, 4096);
  gemm_bt<0><<<dim3(16, 16), 256, 0, stream>>>(emb_d, 512, wihd_bf, 1536, bias_d, gin_d, 2048, 512, 4096);

  // encoder: ONE persistent kernel (128 steps, grid barrier per step)
  enc_persist<<<64, 256, 0, stream>>>(gin_f, gin_b, Whh_f, Whh_b, h_enc, enc_out, enc_out_bf, bar_enc);

  k_h0c0<<<32, 512, 0, stream>>>(h_enc, Wbh, bbh, Wbc, bbc, h_dec, c_dec);

  // enc_proj = enc_out @ Wh_att^T
  gemm_bt<0><<<dim3(4, 16), 256, 0, stream>>>(enc_out_bf, 1024, whatt_bf, 1024, nullptr, enc_proj, 512, 1024, 4096);

  // decoder: ONE persistent kernel (127 steps, 2 grid barriers per step)
  dec_persist<<<64, 512, 0, stream>>>(h_dec, c_dec, wst_pk, v_att, enc_proj, enc_out, src_lens,
                                      gin_d, Wih_d, Whh_d, ctxb, hctx, bar_dec);

  // one big logits GEMM: [2032,1536] x [32000,1536]^T + bfc -> out (B,T-1,V)
  gemm_bt<1><<<dim3(250, 16), 256, 0, stream>>>(hctx, 1536, wfc_bf, 1536, bfc, out, 32000, 1536, 2032);
}

// Round 3
// 7759.940 us; speedup vs baseline: 2.9730x; 2.9730x over previous
//
#include <hip/hip_runtime.h>

typedef __bf16 bf16x8 __attribute__((ext_vector_type(8)));
typedef float f32x4 __attribute__((ext_vector_type(4)));

#define DEV static __device__ __forceinline__

DEV float bf2f(unsigned short u){ union { unsigned u; float f; } x; x.u = ((unsigned)u) << 16; return x.f; }
DEV unsigned short f2bf(float f){
  union { float f; unsigned u; } x; x.f = f;
  unsigned r = x.u + 0x7fffu + ((x.u >> 16) & 1u);
  return (unsigned short)(r >> 16);
}
DEV unsigned pack2(unsigned short lo, unsigned short hi){ return (unsigned)lo | ((unsigned)hi << 16); }
DEV float sigm(float x){ return 1.0f / (1.0f + expf(-x)); }
DEV float tanh_fast(float x){ float e = __expf(2.0f * x); return 1.0f - 2.0f / (e + 1.0f); }
DEV void unpk2(unsigned u, float& a, float& b){ a = bf2f((unsigned short)u); b = bf2f((unsigned short)(u >> 16)); }
DEV bf16x8 pack8(float a0,float a1,float a2,float a3,float a4,float a5,float a6,float a7){
  union { unsigned short s[8]; bf16x8 v; } u;
  u.s[0]=f2bf(a0); u.s[1]=f2bf(a1); u.s[2]=f2bf(a2); u.s[3]=f2bf(a3);
  u.s[4]=f2bf(a4); u.s[5]=f2bf(a5); u.s[6]=f2bf(a6); u.s[7]=f2bf(a7);
  return u.v;
}

// ---- device-scope grid barrier (counter zeroed via memset before launch) ----
DEV void gridbar(unsigned* bar, unsigned target){
  __syncthreads();
  if (threadIdx.x == 0){
    __builtin_amdgcn_fence(__ATOMIC_RELEASE, "agent");
    __hip_atomic_fetch_add(bar, 1u, __ATOMIC_RELAXED, __HIP_MEMORY_SCOPE_AGENT);
    while (__hip_atomic_load(bar, __ATOMIC_RELAXED, __HIP_MEMORY_SCOPE_AGENT) < target)
      __builtin_amdgcn_s_sleep(1);
    __builtin_amdgcn_fence(__ATOMIC_ACQUIRE, "agent");
  }
  __syncthreads();
}

// ---------------- f32 -> bf16 convert ----------------
__global__ void k_f2bf(const float4* __restrict__ in, uint2* __restrict__ out, long n4){
  long stride = (long)gridDim.x * blockDim.x;
  for (long i = (long)blockIdx.x * blockDim.x + threadIdx.x; i < n4; i += stride){
    float4 v = in[i];
    uint2 o; o.x = pack2(f2bf(v.x), f2bf(v.y)); o.y = pack2(f2bf(v.z), f2bf(v.w));
    out[i] = o;
  }
}

// Ws_att [a][k] f32 -> packed bf16 pairs along k: out[kp*512 + a] = (Ws[a][2kp], Ws[a][2kp+1])
__global__ void k_wst(const float* __restrict__ in, unsigned* __restrict__ out){
  int i = blockIdx.x * 256 + threadIdx.x;   // 131072 total
  int kp = i >> 9, a = i & 511;
  const float* r = in + (size_t)a * 512 + 2 * kp;
  out[i] = pack2(f2bf(r[0]), f2bf(r[1]));
}

__global__ void k_bias3(const float* a0, const float* b0, float* o0,
                        const float* a1, const float* b1, float* o1,
                        const float* a2, const float* b2, float* o2){
  int i = blockIdx.x * 256 + threadIdx.x;   // 2048
  o0[i] = a0[i] + b0[i];
  o1[i] = a1[i] + b1[i];
  o2[i] = a2[i] + b2[i];
}

// embedding gather -> bf16 rows. row r = pos*16 + b ; token = tok[b*128 + pos]
__global__ void k_embed(const int* __restrict__ tok, const float* __restrict__ table,
                        unsigned short* __restrict__ out){
  int r = blockIdx.x;
  int b = r & 15, pos = r >> 4;
  int idx = tok[b * 128 + pos];
  float4 v = ((const float4*)(table + (size_t)idx * 512))[threadIdx.x];  // 128 threads
  uint2 o; o.x = pack2(f2bf(v.x), f2bf(v.y)); o.y = pack2(f2bf(v.z), f2bf(v.w));
  ((uint2*)(out + (size_t)r * 512))[threadIdx.x] = o;
}

// ---------------- bf16 MFMA GEMM: C[M,N] = A[M,K] * B[N,K]^T (+bias) ----------------
// MODE 0: f32 C.  MODE 1: logits scatter f32.  MODE 2: bf16 C.
template<int MODE>
__global__ __launch_bounds__(256)
void gemm_bt(const unsigned short* __restrict__ A, int lda,
             const unsigned short* __restrict__ B, int ldb,
             const float* __restrict__ bias,
             void* __restrict__ Cv, int ldc, int K, int mvalid)
{
  __shared__ __align__(16) unsigned short As[128 * 64];
  __shared__ __align__(16) unsigned short Bs[128 * 64];
  const int tid  = threadIdx.x;
  const int lane = tid & 63, wid = tid >> 6;
  const int wm = (wid >> 1) * 64, wn = (wid & 1) * 64;
  const unsigned short* Ab = A + (size_t)blockIdx.y * 128 * lda;
  const unsigned short* Bb = B + (size_t)blockIdx.x * 128 * ldb;

  f32x4 acc[4][4] = {};
  bf16x8 ga[4], gb[4];

  #pragma unroll
  for (int r = 0; r < 4; r++){
    int c = tid + r * 256;
    ga[r] = *(const bf16x8*)(Ab + (size_t)(c >> 3) * lda + (c & 7) * 8);
    gb[r] = *(const bf16x8*)(Bb + (size_t)(c >> 3) * ldb + (c & 7) * 8);
  }
  const int nt = K >> 6;
  for (int t = 0; t < nt; t++){
    #pragma unroll
    for (int r = 0; r < 4; r++){
      int c = tid + r * 256;
      int slot = ((c >> 3) * 8 + ((c & 7) ^ ((c >> 3) & 7))) * 8;
      *(bf16x8*)(As + slot) = ga[r];
      *(bf16x8*)(Bs + slot) = gb[r];
    }
    __syncthreads();
    if (t + 1 < nt){
      int k0 = (t + 1) * 64;
      #pragma unroll
      for (int r = 0; r < 4; r++){
        int c = tid + r * 256;
        ga[r] = *(const bf16x8*)(Ab + (size_t)(c >> 3) * lda + k0 + (c & 7) * 8);
        gb[r] = *(const bf16x8*)(Bb + (size_t)(c >> 3) * ldb + k0 + (c & 7) * 8);
      }
    }
    #pragma unroll
    for (int kk = 0; kk < 2; kk++){
      bf16x8 av[4], bv[4];
      #pragma unroll
      for (int i = 0; i < 4; i++){
        int ra = wm + i * 16 + (lane & 15);
        int ua = (kk * 4 + (lane >> 4)) ^ (ra & 7);
        av[i] = *(const bf16x8*)(As + (ra * 8 + ua) * 8);
        int rb = wn + i * 16 + (lane & 15);
        int ub = (kk * 4 + (lane >> 4)) ^ (rb & 7);
        bv[i] = *(const bf16x8*)(Bs + (rb * 8 + ub) * 8);
      }
      #pragma unroll
      for (int i = 0; i < 4; i++)
        #pragma unroll
        for (int j = 0; j < 4; j++)
          acc[i][j] = __builtin_amdgcn_mfma_f32_16x16x32_bf16(av[i], bv[j], acc[i][j], 0, 0, 0);
    }
    if (t + 1 < nt) __syncthreads();
  }

  const int cb = lane & 15, rb4 = (lane >> 4) * 4;
  #pragma unroll
  for (int i = 0; i < 4; i++){
    #pragma unroll
    for (int j = 0; j < 4; j++){
      #pragma unroll
      for (int r = 0; r < 4; r++){
        int row = blockIdx.y * 128 + wm + i * 16 + rb4 + r;
        int col = blockIdx.x * 128 + wn + j * 16 + cb;
        float v = acc[i][j][r];
        if (bias) v += bias[col];
        if (MODE == 0){
          ((float*)Cv)[(size_t)row * ldc + col] = v;
        } else if (MODE == 2){
          ((unsigned short*)Cv)[(size_t)row * ldc + col] = f2bf(v);
        } else {
          if (row < mvalid){
            int tt = row >> 4, b = row & 15;
            ((float*)Cv)[((size_t)b * 127 + tt) * 32000 + col] = v;
          }
        }
      }
    }
  }
}

// =================================================================================
// Persistent encoder: 128 blocks hold Whh (both dirs) slices in LDS; MFMA per step.
// Block bx owns tile T=bx of each dir: v=0..15 -> n=(v&3)*512 + T*4 + (v>>2).
// Fragment LDS layout: unit u=(kstep*4+chunk)*16+row  (row=lane&15, chunk=lane>>4).
// =================================================================================
__global__ __launch_bounds__(256)
void enc_persist2(const float* __restrict__ gin_f, const float* __restrict__ gin_b,
                  const unsigned short* __restrict__ whhf_bf, const unsigned short* __restrict__ whhb_bf,
                  float* __restrict__ h_enc,   /* [2 parity][2 dir][16][512] f32 */
                  unsigned short* __restrict__ enc_out_bf, /* [16][128][1024] bf16 */
                  unsigned* __restrict__ bar)
{
  __shared__ __align__(16) unsigned short Wt[2][1024][8];   // 32KB weights (resident)
  __shared__ __align__(16) unsigned short Hf[2][1024][8];   // 32KB h-fragments
  __shared__ __align__(16) float P[2][4][64][4];            // 8KB wave partials
  __shared__ float gl[2][16][17];

  const int bx = blockIdx.x, tid = threadIdx.x;
  const int lane = tid & 63, wv = tid >> 6;
  const int T = bx;

  // load weight tiles once
  for (int d = 0; d < 2; d++){
    const unsigned short* src = d ? whhb_bf : whhf_bf;
    for (int u = tid; u < 1024; u += 256){
      int ks = u >> 6, ch = (u >> 4) & 3, v = u & 15;
      int n = (v & 3) * 512 + T * 4 + (v >> 2);
      *(bf16x8*)Wt[d][u] = *(const bf16x8*)(src + (size_t)n * 512 + ks * 32 + ch * 8);
    }
  }

  float creg = 0.0f;                       // cell: tid<128 owns (dir=tid>>6, b=tid&15, joff=(tid>>4)&3)
  const int cd = tid >> 6, cb = tid & 15, cj = (tid >> 4) & 3;
  unsigned tgt = 0;

  for (int t = 0; t < 128; t++){
    const int p = t & 1;
    const float* hp = h_enc + (size_t)p * 16384;
    // stage h (both dirs) as bf16 fragments
    for (int u = tid; u < 2048; u += 256){
      int d = u >> 10, uu = u & 1023;
      int ks = uu >> 6, ch = (uu >> 4) & 3, b = uu & 15;
      const float* s = hp + (size_t)d * 8192 + b * 512 + ks * 32 + ch * 8;
      float4 x0 = *(const float4*)s, x1 = *(const float4*)(s + 4);
      *(bf16x8*)Hf[d][uu] = pack8(x0.x,x0.y,x0.z,x0.w,x1.x,x1.y,x1.z,x1.w);
    }
    __syncthreads();
    #pragma unroll
    for (int d = 0; d < 2; d++){
      f32x4 acc = {};
      #pragma unroll
      for (int m = 0; m < 4; m++){
        int ks = wv * 4 + m;
        int ua = (ks * 4 + (lane >> 4)) * 16 + (lane & 15);
        acc = __builtin_amdgcn_mfma_f32_16x16x32_bf16(*(const bf16x8*)Hf[d][ua],
                                                      *(const bf16x8*)Wt[d][ua], acc, 0, 0, 0);
      }
      *(f32x4*)P[d][wv][lane] = acc;
    }
    __syncthreads();
    if (wv < 2){
      int d = wv;
      f32x4 s0 = *(const f32x4*)P[d][0][lane];
      f32x4 s1 = *(const f32x4*)P[d][1][lane];
      f32x4 s2 = *(const f32x4*)P[d][2][lane];
      f32x4 s3 = *(const f32x4*)P[d][3][lane];
      f32x4 sum = (s0 + s1) + (s2 + s3);
      int v = lane & 15;
      int n = (v & 3) * 512 + T * 4 + (v >> 2);
      int s_in = d ? (127 - t) : t;
      const float* gg = (d ? gin_b : gin_f) + (size_t)s_in * 16 * 2048 + n;
      #pragma unroll
      for (int r = 0; r < 4; r++){
        int b = (lane >> 4) * 4 + r;
        gl[d][v][b] = sum[r] + gg[(size_t)b * 2048];
      }
    }
    __syncthreads();
    if (tid < 128){
      float ig = sigm (gl[cd][cj * 4 + 0][cb]);
      float fg = sigm (gl[cd][cj * 4 + 1][cb]);
      float g2 = tanhf(gl[cd][cj * 4 + 2][cb]);
      float og = sigm (gl[cd][cj * 4 + 3][cb]);
      float cn = fg * creg + ig * g2;
      float hv = og * tanhf(cn);
      creg = cn;
      int j = T * 4 + cj;
      int s_in = cd ? (127 - t) : t;
      h_enc[(size_t)((p ^ 1) * 2 + cd) * 8192 + cb * 512 + j] = hv;
      enc_out_bf[((size_t)cb * 128 + s_in) * 1024 + cd * 512 + j] = f2bf(hv);
    }
    tgt += 128;
    if (t != 127) gridbar(bar, tgt);
  }
}

// ---------------- h0/c0 ----------------
__global__ __launch_bounds__(512)
void k_h0c0(const float* __restrict__ h_enc, const float* __restrict__ Wbh, const float* __restrict__ bbh,
            const float* __restrict__ Wbc, const float* __restrict__ bbc,
            float* __restrict__ h_dec, float* __restrict__ c_dec)
{
  __shared__ float hc[1024];
  int b = blockIdx.x >> 1, which = blockIdx.x & 1;
  int tid = threadIdx.x;
  hc[tid]       = h_enc[b * 512 + tid];          // parity0 dir0 final forward h
  hc[512 + tid] = h_enc[8192 + b * 512 + tid];   // parity0 dir1 final backward h
  __syncthreads();
  const float* W = which ? Wbc : Wbh;
  float acc = (which ? bbc : bbh)[tid];
  const float* wr = W + (size_t)tid * 1024;
  for (int k = 0; k < 1024; k += 4){
    float4 w = *(const float4*)(wr + k);
    acc += w.x * hc[k] + w.y * hc[k + 1] + w.z * hc[k + 2] + w.w * hc[k + 3];
  }
  float v = tanhf(acc);
  if (which) c_dec[b * 512 + tid] = v;
  else       h_dec[b * 512 + tid] = v;
}

// =================================================================================
// Persistent decoder: 128 blocks. LDS-resident weights:
//  - blocks 16..127: Whh_d tiles (bx-16, and 96+bx for bx<32)
//  - all blocks: Wctx tile bx (Wih_d cols 512..1535)
// Phase1: blocks 0..15 attention (b=bx); blocks 16..127 h@Whh -> g1 (+gin). Barrier.
// Phase2: all blocks: ctx@Wctx + g1 -> gates -> cell (j = bx*4+joff). Barrier.
// =================================================================================
__global__ __launch_bounds__(256)
void dec_persist2(float* __restrict__ h_dec, const float* __restrict__ c_dec0,
                  const unsigned* __restrict__ wst_pk, const float* __restrict__ v_att,
                  const unsigned short* __restrict__ enc_proj_bf,
                  const unsigned short* __restrict__ enc_out_bf,
                  const int* __restrict__ src_lens,
                  const float* __restrict__ gin_d,
                  const unsigned short* __restrict__ whhd_bf, const unsigned short* __restrict__ wihd_bf,
                  float* __restrict__ ctx, float* __restrict__ g1,
                  unsigned short* __restrict__ hctx,
                  unsigned* __restrict__ bar)
{
  __shared__ __align__(16) unsigned short Wh[2][1024][8];  // 32KB Whh tiles (resident)
  __shared__ __align__(16) unsigned short Wc[2048][8];     // 32KB Wctx tile (resident)
  __shared__ __align__(16) unsigned short Xf[2048][8];     // 32KB x fragments (h / ctx)
  __shared__ __align__(16) float P[2][4][64][4];           // 8KB wave partials
  __shared__ float gl[16][17];
  __shared__ float hl[512], hs[512], vl[512], att[128];

  const int bx = blockIdx.x, tid = threadIdx.x;
  const int lane = tid & 63, wv = tid >> 6;

  // resident weights
  if (bx >= 16){
    const int ntile = (bx < 32) ? 2 : 1;
    for (int ti = 0; ti < ntile; ti++){
      int TT = ti ? (96 + bx) : (bx - 16);
      for (int u = tid; u < 1024; u += 256){
        int ks = u >> 6, ch = (u >> 4) & 3, v = u & 15;
        int n = (v & 3) * 512 + TT * 4 + (v >> 2);
        *(bf16x8*)Wh[ti][u] = *(const bf16x8*)(whhd_bf + (size_t)n * 512 + ks * 32 + ch * 8);
      }
    }
  }
  for (int u = tid; u < 2048; u += 256){
    int ks = u >> 6, ch = (u >> 4) & 3, v = u & 15;
    int n = (v & 3) * 512 + bx * 4 + (v >> 2);
    *(bf16x8*)Wc[u] = *(const bf16x8*)(wihd_bf + (size_t)n * 1536 + 512 + ks * 32 + ch * 8);
  }
  if (bx < 16){ vl[tid] = v_att[tid]; vl[tid + 256] = v_att[tid + 256]; }

  float creg = 0.0f;                 // tid<64 owns (b=tid&15, j=bx*4+(tid>>4))
  if (tid < 64) creg = c_dec0[(tid & 15) * 512 + bx * 4 + (tid >> 4)];
  unsigned tgt = 0;

  for (int t = 0; t < 127; t++){
    const int p = t & 1;
    const float* h = h_dec + (size_t)p * 8192;
    float* hn      = h_dec + (size_t)(p ^ 1) * 8192;

    if (bx < 16){
      // ---------------- attention for batch b = bx ----------------
      const int b = bx;
      hl[tid] = h[b * 512 + tid];
      hl[tid + 256] = h[b * 512 + 256 + tid];
      __syncthreads();
      {
        float s0a = 0.f, s1a = 0.f, s0b = 0.f, s1b = 0.f;
        for (int kp = 0; kp < 256; kp++){
          unsigned ua = wst_pk[kp * 512 + tid];
          unsigned ub = wst_pk[kp * 512 + 256 + tid];
          float h0 = hl[2 * kp], h1 = hl[2 * kp + 1];
          s0a += h0 * bf2f((unsigned short)ua); s1a += h1 * bf2f((unsigned short)(ua >> 16));
          s0b += h0 * bf2f((unsigned short)ub); s1b += h1 * bf2f((unsigned short)(ub >> 16));
        }
        hs[tid] = s0a + s1a; hs[tid + 256] = s0b + s1b;
      }
      __syncthreads();
      {
        const int s = tid >> 1, part = tid & 1;
        const unsigned short* ep = enc_proj_bf + (size_t)(b * 128 + s) * 512 + part * 256;
        const float* hsp = hs + part * 256;
        const float* vp  = vl + part * 256;
        float sv = 0.f;
        for (int a = 0; a < 256; a += 8){
          uint4 u = *(const uint4*)(ep + a);
          float e0,e1,e2,e3,e4,e5,e6,e7;
          unpk2(u.x,e0,e1); unpk2(u.y,e2,e3); unpk2(u.z,e4,e5); unpk2(u.w,e6,e7);
          sv += vp[a+0]*tanh_fast(e0+hsp[a+0]) + vp[a+1]*tanh_fast(e1+hsp[a+1])
              + vp[a+2]*tanh_fast(e2+hsp[a+2]) + vp[a+3]*tanh_fast(e3+hsp[a+3])
              + vp[a+4]*tanh_fast(e4+hsp[a+4]) + vp[a+5]*tanh_fast(e5+hsp[a+5])
              + vp[a+6]*tanh_fast(e6+hsp[a+6]) + vp[a+7]*tanh_fast(e7+hsp[a+7]);
        }
        sv += __shfl_xor(sv, 1);
        if (part == 0) att[s] = sv;
      }
      __syncthreads();
      if (tid < 64){
        int slen = src_lens[b];
        float x0 = (tid < slen)      ? att[tid]      : -1e9f;
        float x1 = (tid + 64 < slen) ? att[tid + 64] : -1e9f;
        float m = fmaxf(x0, x1);
        #pragma unroll
        for (int o = 32; o; o >>= 1) m = fmaxf(m, __shfl_xor(m, o));
        float e0 = expf(x0 - m), e1 = expf(x1 - m);
        float ssum = e0 + e1;
        #pragma unroll
        for (int o = 32; o; o >>= 1) ssum += __shfl_xor(ssum, o);
        float inv = 1.0f / ssum;
        att[tid] = e0 * inv; att[tid + 64] = e1 * inv;
      }
      __syncthreads();
      {
        const unsigned short* eo = enc_out_bf + (size_t)b * 131072 + 4 * tid;
        float c0=0.f,c1=0.f,c2=0.f,c3=0.f;
        for (int s2 = 0; s2 < 128; s2++){
          float a = att[s2];
          uint2 u = *(const uint2*)(eo + (size_t)s2 * 1024);
          float e0,e1,e2,e3; unpk2(u.x,e0,e1); unpk2(u.y,e2,e3);
          c0 += a*e0; c1 += a*e1; c2 += a*e2; c3 += a*e3;
        }
        float4 cv4; cv4.x=c0; cv4.y=c1; cv4.z=c2; cv4.w=c3;
        *(float4*)(ctx + b * 1024 + 4 * tid) = cv4;
        size_t row = (size_t)t * 16 + b;
        uint2 pk; pk.x = pack2(f2bf(c0), f2bf(c1)); pk.y = pack2(f2bf(c2), f2bf(c3));
        *(uint2*)(hctx + row * 1536 + 512 + 4 * tid) = pk;
      }
    } else {
      // ---------------- h @ Whh^T for owned tiles ----------------
      for (int u = tid; u < 1024; u += 256){
        int ks = u >> 6, ch = (u >> 4) & 3, b = u & 15;
        const float* s = h + b * 512 + ks * 32 + ch * 8;
        float4 x0 = *(const float4*)s, x1 = *(const float4*)(s + 4);
        *(bf16x8*)Xf[u] = pack8(x0.x,x0.y,x0.z,x0.w,x1.x,x1.y,x1.z,x1.w);
      }
      __syncthreads();
      const int ntile = (bx < 32) ? 2 : 1;
      for (int ti = 0; ti < ntile; ti++){
        f32x4 acc = {};
        #pragma unroll
        for (int m = 0; m < 4; m++){
          int ks = wv * 4 + m;
          int ua = (ks * 4 + (lane >> 4)) * 16 + (lane & 15);
          acc = __builtin_amdgcn_mfma_f32_16x16x32_bf16(*(const bf16x8*)Xf[ua],
                                                        *(const bf16x8*)Wh[ti][ua], acc, 0, 0, 0);
        }
        *(f32x4*)P[ti][wv][lane] = acc;
      }
      __syncthreads();
      if (wv < ntile){
        f32x4 s0 = *(const f32x4*)P[wv][0][lane];
        f32x4 s1 = *(const f32x4*)P[wv][1][lane];
        f32x4 s2 = *(const f32x4*)P[wv][2][lane];
        f32x4 s3 = *(const f32x4*)P[wv][3][lane];
        f32x4 sum = (s0 + s1) + (s2 + s3);
        int TT = wv ? (96 + bx) : (bx - 16);
        int v = lane & 15;
        int n = (v & 3) * 512 + TT * 4 + (v >> 2);
        #pragma unroll
        for (int r = 0; r < 4; r++)
          sum[r] += gin_d[((size_t)t * 16 + ((lane >> 4) * 4 + r)) * 2048 + n];
        *(f32x4*)(g1 + ((size_t)TT * 64 + lane) * 4) = sum;
      }
    }

    tgt += 128;
    gridbar(bar, tgt);

    // ---------------- phase 2: ctx @ Wctx + g1 -> gates -> cell ----------------
    for (int u = tid; u < 2048; u += 256){
      int ks = u >> 6, ch = (u >> 4) & 3, b = u & 15;
      const float* s = ctx + b * 1024 + ks * 32 + ch * 8;
      float4 x0 = *(const float4*)s, x1 = *(const float4*)(s + 4);
      *(bf16x8*)Xf[u] = pack8(x0.x,x0.y,x0.z,x0.w,x1.x,x1.y,x1.z,x1.w);
    }
    __syncthreads();
    {
      f32x4 acc = {};
      if (wv == 0) acc = *(const f32x4*)(g1 + ((size_t)bx * 64 + lane) * 4);
      #pragma unroll
      for (int m = 0; m < 8; m++){
        int ks = wv * 8 + m;
        int ua = (ks * 4 + (lane >> 4)) * 16 + (lane & 15);
        acc = __builtin_amdgcn_mfma_f32_16x16x32_bf16(*(const bf16x8*)Xf[ua],
                                                      *(const bf16x8*)Wc[ua], acc, 0, 0, 0);
      }
      *(f32x4*)P[0][wv][lane] = acc;
    }
    __syncthreads();
    if (wv == 0){
      f32x4 s0 = *(const f32x4*)P[0][0][lane];
      f32x4 s1 = *(const f32x4*)P[0][1][lane];
      f32x4 s2 = *(const f32x4*)P[0][2][lane];
      f32x4 s3 = *(const f32x4*)P[0][3][lane];
      f32x4 sum = (s0 + s1) + (s2 + s3);
      int v = lane & 15;
      #pragma unroll
      for (int r = 0; r < 4; r++) gl[v][(lane >> 4) * 4 + r] = sum[r];
    }
    __syncthreads();
    if (tid < 64){
      int b2 = tid & 15, joff = tid >> 4;
      float ig = sigm (gl[joff * 4 + 0][b2]);
      float fg = sigm (gl[joff * 4 + 1][b2]);
      float g2 = tanhf(gl[joff * 4 + 2][b2]);
      float og = sigm (gl[joff * 4 + 3][b2]);
      float cn = fg * creg + ig * g2;
      float hv = og * tanhf(cn);
      creg = cn;
      int j = bx * 4 + joff;
      hn[b2 * 512 + j] = hv;
      hctx[((size_t)t * 16 + b2) * 1536 + j] = f2bf(hv);
    }
    tgt += 128;
    if (t != 126) gridbar(bar, tgt);
  }
}

extern "C" void kernel_launch(void* const* d_in, const int* in_sizes, int n_in,
                              void* d_out, int out_size, void* d_ws, size_t ws_size,
                              hipStream_t stream)
{
  const int*   src       = (const int*)d_in[0];
  const int*   src_lens  = (const int*)d_in[1];
  const int*   tgt       = (const int*)d_in[2];
  const float* enc_embed = (const float*)d_in[3];
  const float* Wih_f = (const float*)d_in[4];
  const float* Whh_f = (const float*)d_in[5];
  const float* bih_f = (const float*)d_in[6];
  const float* bhh_f = (const float*)d_in[7];
  const float* Wih_b = (const float*)d_in[8];
  const float* Whh_b = (const float*)d_in[9];
  const float* bih_b = (const float*)d_in[10];
  const float* bhh_b = (const float*)d_in[11];
  const float* Wbh = (const float*)d_in[12];
  const float* bbh = (const float*)d_in[13];
  const float* Wbc = (const float*)d_in[14];
  const float* bbc = (const float*)d_in[15];
  const float* Wh_att = (const float*)d_in[16];
  const float* Ws_att = (const float*)d_in[17];
  const float* v_att  = (const float*)d_in[18];
  const float* dec_embed = (const float*)d_in[19];
  const float* Wih_d = (const float*)d_in[20];
  const float* Whh_d = (const float*)d_in[21];
  const float* bih_d = (const float*)d_in[22];
  const float* bhh_d = (const float*)d_in[23];
  const float* Wfc = (const float*)d_in[24];
  const float* bfc = (const float*)d_in[25];
  float* out = (float*)d_out;

  char* base = (char*)d_ws;
  size_t off = 0;
  auto take = [&](size_t bytes) -> char* {
    char* p = base + off;
    off += (bytes + 255) & ~(size_t)255;
    return p;
  };
  unsigned short* wfc_bf    = (unsigned short*)take((size_t)32000 * 1536 * 2);
  unsigned short* emb_e     = (unsigned short*)take((size_t)2048 * 512 * 2);
  unsigned short* emb_d     = (unsigned short*)take((size_t)2048 * 512 * 2);
  unsigned short* wihf_bf   = (unsigned short*)take((size_t)2048 * 512 * 2);
  unsigned short* wihb_bf   = (unsigned short*)take((size_t)2048 * 512 * 2);
  unsigned short* wihd_bf   = (unsigned short*)take((size_t)2048 * 1536 * 2);
  unsigned short* whhf_bf   = (unsigned short*)take((size_t)2048 * 512 * 2);
  unsigned short* whhb_bf   = (unsigned short*)take((size_t)2048 * 512 * 2);
  unsigned short* whhd_bf   = (unsigned short*)take((size_t)2048 * 512 * 2);
  unsigned short* whatt_bf  = (unsigned short*)take((size_t)512 * 1024 * 2);
  unsigned*       wst_pk    = (unsigned*)take((size_t)256 * 512 * 4);
  float* gin_f    = (float*)take((size_t)2048 * 2048 * 4);
  float* gin_b    = (float*)take((size_t)2048 * 2048 * 4);
  float* gin_d    = (float*)take((size_t)2048 * 2048 * 4);
  unsigned short* enc_out_bf  = (unsigned short*)take((size_t)2048 * 1024 * 2);
  unsigned short* enc_proj_bf = (unsigned short*)take((size_t)2048 * 512 * 2);
  unsigned short* hctx = (unsigned short*)take((size_t)2048 * 1536 * 2);
  float* g1    = (float*)take((size_t)128 * 64 * 4 * 4);
  float* h_enc = (float*)take((size_t)2 * 2 * 16 * 512 * 4);
  float* h_dec = (float*)take((size_t)2 * 16 * 512 * 4);
  float* c_dec = (float*)take((size_t)16 * 512 * 4);
  float* ctxb  = (float*)take((size_t)16 * 1024 * 4);
  float* bias_f = (float*)take(2048 * 4);
  float* bias_b = (float*)take(2048 * 4);
  float* bias_d = (float*)take(2048 * 4);
  unsigned* barbuf = (unsigned*)take(256);
  unsigned* bar_enc = barbuf;
  unsigned* bar_dec = barbuf + 32;

  // zero: state region (h_enc..ctxb), padded dec-embedding rows, padded hctx rows, barriers
  hipMemsetAsync(h_enc, 0, (size_t)((char*)ctxb - (char*)h_enc) + 16 * 1024 * 4, stream);
  hipMemsetAsync(emb_d, 0, (size_t)2048 * 512 * 2, stream);
  hipMemsetAsync(hctx, 0, (size_t)2048 * 1536 * 2, stream);
  hipMemsetAsync(barbuf, 0, 256, stream);

  // weight conversions
  k_f2bf<<<4096, 256, 0, stream>>>((const float4*)Wfc,   (uint2*)wfc_bf,   (long)32000 * 1536 / 4);
  k_f2bf<<<512,  256, 0, stream>>>((const float4*)Wih_f, (uint2*)wihf_bf,  (long)2048 * 512 / 4);
  k_f2bf<<<512,  256, 0, stream>>>((const float4*)Wih_b, (uint2*)wihb_bf,  (long)2048 * 512 / 4);
  k_f2bf<<<1024, 256, 0, stream>>>((const float4*)Wih_d, (uint2*)wihd_bf,  (long)2048 * 1536 / 4);
  k_f2bf<<<512,  256, 0, stream>>>((const float4*)Whh_f, (uint2*)whhf_bf,  (long)2048 * 512 / 4);
  k_f2bf<<<512,  256, 0, stream>>>((const float4*)Whh_b, (uint2*)whhb_bf,  (long)2048 * 512 / 4);
  k_f2bf<<<512,  256, 0, stream>>>((const float4*)Whh_d, (uint2*)whhd_bf,  (long)2048 * 512 / 4);
  k_f2bf<<<512,  256, 0, stream>>>((const float4*)Wh_att,(uint2*)whatt_bf, (long)512 * 1024 / 4);
  k_wst<<<512, 256, 0, stream>>>(Ws_att, wst_pk);
  k_bias3<<<8, 256, 0, stream>>>(bih_f, bhh_f, bias_f, bih_b, bhh_b, bias_b, bih_d, bhh_d, bias_d);

  // embeddings (bf16), rows r = pos*16 + b
  k_embed<<<2048, 128, 0, stream>>>(src, enc_embed, emb_e);
  k_embed<<<2032, 128, 0, stream>>>(tgt, dec_embed, emb_d);

  // input-side gate GEMMs (hoisted out of the scans)
  gemm_bt<0><<<dim3(16, 16), 256, 0, stream>>>(emb_e, 512, wihf_bf, 512,  bias_f, gin_f, 2048, 512, 4096);
  gemm_bt<0><<<dim3(16, 16), 256, 0, stream>>>(emb_e, 512, wihb_bf, 512,  bias_b, gin_b, 2048, 512, 4096);
  gemm_bt<0><<<dim3(16, 16), 256, 0, stream>>>(emb_d, 512, wihd_bf, 1536, bias_d, gin_d, 2048, 512, 4096);

  // encoder: persistent, LDS-resident recurrent weights
  enc_persist2<<<128, 256, 0, stream>>>(gin_f, gin_b, whhf_bf, whhb_bf, h_enc, enc_out_bf, bar_enc);

  k_h0c0<<<32, 512, 0, stream>>>(h_enc, Wbh, bbh, Wbc, bbc, h_dec, c_dec);

  // enc_proj (bf16 out) = enc_out @ Wh_att^T
  gemm_bt<2><<<dim3(4, 16), 256, 0, stream>>>(enc_out_bf, 1024, whatt_bf, 1024, nullptr, enc_proj_bf, 512, 1024, 4096);

  // decoder: persistent, LDS-resident recurrent weights
  dec_persist2<<<128, 256, 0, stream>>>(h_dec, c_dec, wst_pk, v_att, enc_proj_bf, enc_out_bf, src_lens,
                                        gin_d, whhd_bf, wihd_bf, ctxb, g1, hctx, bar_dec);

  // one big logits GEMM: [2032,1536] x [32000,1536]^T + bfc -> out (B,T-1,V)
  gemm_bt<1><<<dim3(250, 16), 256, 0, stream>>>(hctx, 1536, wfc_bf, 1536, bfc, out, 32000, 1536, 2032);
}

// Round 4
// 6898.721 us; speedup vs baseline: 3.3441x; 1.1248x over previous
//
#include <hip/hip_runtime.h>

typedef __bf16 bf16x8 __attribute__((ext_vector_type(8)));
typedef float f32x4 __attribute__((ext_vector_type(4)));
typedef unsigned short us;

#define DEV static __device__ __forceinline__

DEV float bf2f(us u){ union { unsigned u; float f; } x; x.u = ((unsigned)u) << 16; return x.f; }
DEV us f2bf(float f){
  union { float f; unsigned u; } x; x.f = f;
  unsigned r = x.u + 0x7fffu + ((x.u >> 16) & 1u);
  return (us)(r >> 16);
}
DEV unsigned pack2(us lo, us hi){ return (unsigned)lo | ((unsigned)hi << 16); }
DEV float sigm(float x){ return 1.0f / (1.0f + expf(-x)); }
DEV float tanh_fast(float x){ float e = __expf(2.0f * x); return 1.0f - 2.0f / (e + 1.0f); }
DEV void unpk2(unsigned u, float& a, float& b){ a = bf2f((us)u); b = bf2f((us)(u >> 16)); }

// ---- flag-based grid barrier: per-block arrival stores (own cacheline each),
// ---- master block (nb-1) aggregates, 8 replicated release lines. No RMW.
DEV void gridbar2(unsigned* arr, unsigned* rel, unsigned ep, int nb){
  __syncthreads();
  const int tid = threadIdx.x, bid = blockIdx.x;
  if (tid == 0){
    __builtin_amdgcn_fence(__ATOMIC_RELEASE, "agent");
    __hip_atomic_store(arr + bid * 32, ep, __ATOMIC_RELAXED, __HIP_MEMORY_SCOPE_AGENT);
  }
  if (bid == nb - 1){
    for (int i = tid; i < nb; i += 256){
      while (__hip_atomic_load(arr + i * 32, __ATOMIC_RELAXED, __HIP_MEMORY_SCOPE_AGENT) < ep)
        __builtin_amdgcn_s_sleep(1);
    }
    __syncthreads();
    __builtin_amdgcn_fence(__ATOMIC_ACQ_REL, "agent");
    if (tid < 8)
      __hip_atomic_store(rel + tid * 32, ep, __ATOMIC_RELAXED, __HIP_MEMORY_SCOPE_AGENT);
  } else if (tid == 0){
    while (__hip_atomic_load(rel + (bid & 7) * 32, __ATOMIC_RELAXED, __HIP_MEMORY_SCOPE_AGENT) < ep)
      __builtin_amdgcn_s_sleep(1);
    __builtin_amdgcn_fence(__ATOMIC_ACQUIRE, "agent");
  }
  __syncthreads();
}

// ---------------- f32 -> bf16 convert ----------------
__global__ void k_f2bf(const float4* __restrict__ in, uint2* __restrict__ out, long n4){
  long stride = (long)gridDim.x * blockDim.x;
  for (long i = (long)blockIdx.x * blockDim.x + threadIdx.x; i < n4; i += stride){
    float4 v = in[i];
    uint2 o; o.x = pack2(f2bf(v.x), f2bf(v.y)); o.y = pack2(f2bf(v.z), f2bf(v.w));
    out[i] = o;
  }
}

// Ws_att [a][k] f32 -> packed bf16 pairs along k: out[kp*512 + a] = (Ws[a][2kp], Ws[a][2kp+1])
__global__ void k_wst(const float* __restrict__ in, unsigned* __restrict__ out){
  int i = blockIdx.x * 256 + threadIdx.x;   // 131072 total
  int kp = i >> 9, a = i & 511;
  const float* r = in + (size_t)a * 512 + 2 * kp;
  out[i] = pack2(f2bf(r[0]), f2bf(r[1]));
}

__global__ void k_bias3(const float* a0, const float* b0, float* o0,
                        const float* a1, const float* b1, float* o1,
                        const float* a2, const float* b2, float* o2){
  int i = blockIdx.x * 256 + threadIdx.x;   // 2048
  o0[i] = a0[i] + b0[i];
  o1[i] = a1[i] + b1[i];
  o2[i] = a2[i] + b2[i];
}

// embedding gather -> bf16 rows. row r = pos*16 + b ; token = tok[b*128 + pos]
__global__ void k_embed(const int* __restrict__ tok, const float* __restrict__ table,
                        us* __restrict__ out){
  int r = blockIdx.x;
  int b = r & 15, pos = r >> 4;
  int idx = tok[b * 128 + pos];
  float4 v = ((const float4*)(table + (size_t)idx * 512))[threadIdx.x];  // 128 threads
  uint2 o; o.x = pack2(f2bf(v.x), f2bf(v.y)); o.y = pack2(f2bf(v.z), f2bf(v.w));
  ((uint2*)(out + (size_t)r * 512))[threadIdx.x] = o;
}

// ---------------- bf16 MFMA GEMM: C[M,N] = A[M,K] * B[N,K]^T (+bias) ----------------
// MODE 0: f32 C.  MODE 1: logits scatter f32.  MODE 2: bf16 C.
template<int MODE>
__global__ __launch_bounds__(256)
void gemm_bt(const us* __restrict__ A, int lda,
             const us* __restrict__ B, int ldb,
             const float* __restrict__ bias,
             void* __restrict__ Cv, int ldc, int K, int mvalid)
{
  __shared__ __align__(16) us As[128 * 64];
  __shared__ __align__(16) us Bs[128 * 64];
  const int tid  = threadIdx.x;
  const int lane = tid & 63, wid = tid >> 6;
  const int wm = (wid >> 1) * 64, wn = (wid & 1) * 64;
  const us* Ab = A + (size_t)blockIdx.y * 128 * lda;
  const us* Bb = B + (size_t)blockIdx.x * 128 * ldb;

  f32x4 acc[4][4] = {};
  bf16x8 ga[4], gb[4];

  #pragma unroll
  for (int r = 0; r < 4; r++){
    int c = tid + r * 256;
    ga[r] = *(const bf16x8*)(Ab + (size_t)(c >> 3) * lda + (c & 7) * 8);
    gb[r] = *(const bf16x8*)(Bb + (size_t)(c >> 3) * ldb + (c & 7) * 8);
  }
  const int nt = K >> 6;
  for (int t = 0; t < nt; t++){
    #pragma unroll
    for (int r = 0; r < 4; r++){
      int c = tid + r * 256;
      int slot = ((c >> 3) * 8 + ((c & 7) ^ ((c >> 3) & 7))) * 8;
      *(bf16x8*)(As + slot) = ga[r];
      *(bf16x8*)(Bs + slot) = gb[r];
    }
    __syncthreads();
    if (t + 1 < nt){
      int k0 = (t + 1) * 64;
      #pragma unroll
      for (int r = 0; r < 4; r++){
        int c = tid + r * 256;
        ga[r] = *(const bf16x8*)(Ab + (size_t)(c >> 3) * lda + k0 + (c & 7) * 8);
        gb[r] = *(const bf16x8*)(Bb + (size_t)(c >> 3) * ldb + k0 + (c & 7) * 8);
      }
    }
    #pragma unroll
    for (int kk = 0; kk < 2; kk++){
      bf16x8 av[4], bv[4];
      #pragma unroll
      for (int i = 0; i < 4; i++){
        int ra = wm + i * 16 + (lane & 15);
        int ua = (kk * 4 + (lane >> 4)) ^ (ra & 7);
        av[i] = *(const bf16x8*)(As + (ra * 8 + ua) * 8);
        int rb = wn + i * 16 + (lane & 15);
        int ub = (kk * 4 + (lane >> 4)) ^ (rb & 7);
        bv[i] = *(const bf16x8*)(Bs + (rb * 8 + ub) * 8);
      }
      #pragma unroll
      for (int i = 0; i < 4; i++)
        #pragma unroll
        for (int j = 0; j < 4; j++)
          acc[i][j] = __builtin_amdgcn_mfma_f32_16x16x32_bf16(av[i], bv[j], acc[i][j], 0, 0, 0);
    }
    if (t + 1 < nt) __syncthreads();
  }

  const int cb = lane & 15, rb4 = (lane >> 4) * 4;
  #pragma unroll
  for (int i = 0; i < 4; i++){
    #pragma unroll
    for (int j = 0; j < 4; j++){
      #pragma unroll
      for (int r = 0; r < 4; r++){
        int row = blockIdx.y * 128 + wm + i * 16 + rb4 + r;
        int col = blockIdx.x * 128 + wn + j * 16 + cb;
        float v = acc[i][j][r];
        if (bias) v += bias[col];
        if (MODE == 0){
          ((float*)Cv)[(size_t)row * ldc + col] = v;
        } else if (MODE == 2){
          ((us*)Cv)[(size_t)row * ldc + col] = f2bf(v);
        } else {
          if (row < mvalid){
            int tt = row >> 4, b = row & 15;
            ((float*)Cv)[((size_t)b * 127 + tt) * 32000 + col] = v;
          }
        }
      }
    }
  }
}

// =================================================================================
// Persistent encoder v3: 128 blocks; Whh tiles (both dirs) LDS-resident; h state
// lives only as bf16 in enc_out_bf (stage = raw 16B copies). 1 barrier/step.
// Block bx owns j = bx*4..bx*4+3 for both dirs: v=0..15 -> n=(v&3)*512+bx*4+(v>>2).
// =================================================================================
__global__ __launch_bounds__(256)
void enc_persist3(const float* __restrict__ gin_f, const float* __restrict__ gin_b,
                  const us* __restrict__ whhf_bf, const us* __restrict__ whhb_bf,
                  us* __restrict__ enc_out_bf, /* [16][128][1024] bf16 */
                  unsigned* __restrict__ arr, unsigned* __restrict__ rel)
{
  __shared__ __align__(16) us Wt[2][1024][8];   // 32KB resident weights
  __shared__ __align__(16) us Hf[2][1024][8];   // 32KB h fragments
  __shared__ __align__(16) f32x4 P[2][4][64];   // 8KB partials
  __shared__ float gl[2][16][17];

  const int bx = blockIdx.x, tid = threadIdx.x;
  const int lane = tid & 63, wv = tid >> 6;

  for (int d = 0; d < 2; d++){
    const us* srcw = d ? whhb_bf : whhf_bf;
    for (int u = tid; u < 1024; u += 256){
      int ks = u >> 6, ch = (u >> 4) & 3, v = u & 15;
      int n = (v & 3) * 512 + bx * 4 + (v >> 2);
      *(bf16x8*)Wt[d][u] = *(const bf16x8*)(srcw + (size_t)n * 512 + ks * 32 + ch * 8);
    }
  }

  float creg = 0.0f;                       // tid<128 owns (dir=tid>>6, b=tid&15, jo=(tid>>4)&3)
  const int cd = (tid >> 6) & 1, cb = tid & 15, cj = (tid >> 4) & 3;

  for (int t = 0; t < 128; t++){
    if (t == 0){
      bf16x8 z = {};
      for (int u = tid; u < 2048; u += 256) *(bf16x8*)Hf[u >> 10][u & 1023] = z;
    } else {
      for (int u = tid; u < 2048; u += 256){
        int d = u >> 10, uu = u & 1023;
        int ks = uu >> 6, ch = (uu >> 4) & 3, b = uu & 15;
        int sp = d ? (128 - t) : (t - 1);
        *(bf16x8*)Hf[d][uu] =
          *(const bf16x8*)(enc_out_bf + ((size_t)b * 128 + sp) * 1024 + d * 512 + ks * 32 + ch * 8);
      }
    }
    __syncthreads();
    #pragma unroll
    for (int d = 0; d < 2; d++){
      f32x4 acc = {};
      #pragma unroll
      for (int m = 0; m < 4; m++){
        int ks = wv * 4 + m;
        int ua = (ks * 4 + (lane >> 4)) * 16 + (lane & 15);
        acc = __builtin_amdgcn_mfma_f32_16x16x32_bf16(*(const bf16x8*)Hf[d][ua],
                                                      *(const bf16x8*)Wt[d][ua], acc, 0, 0, 0);
      }
      P[d][wv][lane] = acc;
    }
    __syncthreads();
    if (wv < 2){
      int d = wv;
      f32x4 sum = (P[d][0][lane] + P[d][1][lane]) + (P[d][2][lane] + P[d][3][lane]);
      int v = lane & 15;
      int n = (v & 3) * 512 + bx * 4 + (v >> 2);
      int s_in = d ? (127 - t) : t;
      const float* gg = (d ? gin_b : gin_f) + (size_t)s_in * 16 * 2048 + n;
      #pragma unroll
      for (int r = 0; r < 4; r++){
        int b = (lane >> 4) * 4 + r;
        gl[d][v][b] = sum[r] + gg[(size_t)b * 2048];
      }
    }
    __syncthreads();
    if (tid < 128){
      float ig = sigm (gl[cd][cj * 4 + 0][cb]);
      float fg = sigm (gl[cd][cj * 4 + 1][cb]);
      float g2 = tanhf(gl[cd][cj * 4 + 2][cb]);
      float og = sigm (gl[cd][cj * 4 + 3][cb]);
      float cn = fg * creg + ig * g2;
      float hv = og * tanhf(cn);
      creg = cn;
      int j = bx * 4 + cj;
      int s_in = cd ? (127 - t) : t;
      enc_out_bf[((size_t)cb * 128 + s_in) * 1024 + cd * 512 + j] = f2bf(hv);
    }
    if (t != 127) gridbar2(arr, rel, t + 1, 128);
  }
}

// ---------------- h0/c0 (reads bf16 finals, writes h0 bf16 + c0 f32) ----------------
__global__ __launch_bounds__(512)
void k_h0c0(const us* __restrict__ enc_out_bf, const float* __restrict__ Wbh, const float* __restrict__ bbh,
            const float* __restrict__ Wbc, const float* __restrict__ bbc,
            us* __restrict__ h0_bf, float* __restrict__ c_dec)
{
  __shared__ float hc[1024];
  int b = blockIdx.x >> 1, which = blockIdx.x & 1;
  int tid = threadIdx.x;
  hc[tid]       = bf2f(enc_out_bf[((size_t)b * 128 + 127) * 1024 + tid]);        // fwd final h
  hc[512 + tid] = bf2f(enc_out_bf[((size_t)b * 128 + 0)   * 1024 + 512 + tid]);  // bwd final h
  __syncthreads();
  const float* W = which ? Wbc : Wbh;
  float acc = (which ? bbc : bbh)[tid];
  const float* wr = W + (size_t)tid * 1024;
  for (int k = 0; k < 1024; k += 4){
    float4 w = *(const float4*)(wr + k);
    acc += w.x * hc[k] + w.y * hc[k + 1] + w.z * hc[k + 2] + w.w * hc[k + 3];
  }
  float v = tanhf(acc);
  if (which) c_dec[b * 512 + tid] = v;
  else       h0_bf[b * 512 + tid] = f2bf(v);
}

// =================================================================================
// Persistent decoder v3: 128 blocks, each owns j = bx*4..bx*4+3 (all 4 gates) with
// Whh rows (16KB) + Wctx rows (32KB) LDS-resident. h/ctx live as bf16 in hctx rows.
// Phase A: all blocks h@Whh (partial -> LDS); blocks 0..15 attention -> ctx (bf16).
// Barrier. Phase B: ctx@Wctx + partial -> gates -> cell -> h_{t+1} into hctx row t.
// Barrier. 2 barriers/step, no g1 global round-trip.
// =================================================================================
__global__ __launch_bounds__(256)
void dec_persist3(const us* __restrict__ h0_bf, const float* __restrict__ c_dec0,
                  const unsigned* __restrict__ wst_pk, const float* __restrict__ v_att,
                  const us* __restrict__ enc_proj_bf,
                  const us* __restrict__ enc_out_bf,
                  const int* __restrict__ src_lens,
                  const float* __restrict__ gin_d,
                  const us* __restrict__ whhd_bf, const us* __restrict__ wihd_bf,
                  us* __restrict__ hctx,
                  unsigned* __restrict__ arr, unsigned* __restrict__ rel)
{
  __shared__ __align__(16) us Wh[1024][8];     // 16KB Whh rows (resident)
  __shared__ __align__(16) us Wc[2048][8];     // 32KB Wctx rows (resident)
  __shared__ __align__(16) us Xf[2048][8];     // 32KB fragments (h then ctx)
  __shared__ __align__(16) f32x4 P[4][64];     // 4KB partials
  __shared__ float g1l[16][17];
  __shared__ float gl[16][17];
  __shared__ float hl[512], hs[512], vl[512], att[128];

  const int bx = blockIdx.x, tid = threadIdx.x;
  const int lane = tid & 63, wv = tid >> 6;

  for (int u = tid; u < 1024; u += 256){
    int ks = u >> 6, ch = (u >> 4) & 3, v = u & 15;
    int n = (v & 3) * 512 + bx * 4 + (v >> 2);
    *(bf16x8*)Wh[u] = *(const bf16x8*)(whhd_bf + (size_t)n * 512 + ks * 32 + ch * 8);
  }
  for (int u = tid; u < 2048; u += 256){
    int ks = u >> 6, ch = (u >> 4) & 3, v = u & 15;
    int n = (v & 3) * 512 + bx * 4 + (v >> 2);
    *(bf16x8*)Wc[u] = *(const bf16x8*)(wihd_bf + (size_t)n * 1536 + 512 + ks * 32 + ch * 8);
  }
  if (bx < 16){ vl[tid] = v_att[tid]; vl[tid + 256] = v_att[tid + 256]; }

  float creg = 0.0f;                 // tid<64 owns (b=tid&15, j=bx*4+(tid>>4))
  if (tid < 64) creg = c_dec0[(tid & 15) * 512 + bx * 4 + (tid >> 4)];

  for (int t = 0; t < 127; t++){
    const us* hsrc = t ? (hctx + (size_t)(t - 1) * 16 * 1536) : h0_bf;
    const int hstride = t ? 1536 : 512;

    // -------- phase A: stage h, h@Whh partial; blocks 0..15 attention --------
    for (int u = tid; u < 1024; u += 256){
      int ks = u >> 6, ch = (u >> 4) & 3, b = u & 15;
      *(bf16x8*)Xf[u] = *(const bf16x8*)(hsrc + (size_t)b * hstride + ks * 32 + ch * 8);
    }
    if (bx < 16){
      const us* hb = hsrc + (size_t)bx * hstride;
      hl[tid] = bf2f(hb[tid]); hl[tid + 256] = bf2f(hb[tid + 256]);
    }
    __syncthreads();
    {
      f32x4 acc = {};
      #pragma unroll
      for (int m = 0; m < 4; m++){
        int ks = wv * 4 + m;
        int ua = (ks * 4 + (lane >> 4)) * 16 + (lane & 15);
        acc = __builtin_amdgcn_mfma_f32_16x16x32_bf16(*(const bf16x8*)Xf[ua],
                                                      *(const bf16x8*)Wh[ua], acc, 0, 0, 0);
      }
      P[wv][lane] = acc;
    }
    __syncthreads();
    if (wv == 0){
      f32x4 sum = (P[0][lane] + P[1][lane]) + (P[2][lane] + P[3][lane]);
      int v = lane & 15;
      int n = (v & 3) * 512 + bx * 4 + (v >> 2);
      #pragma unroll
      for (int r = 0; r < 4; r++){
        int b = (lane >> 4) * 4 + r;
        g1l[v][b] = sum[r] + gin_d[((size_t)t * 16 + b) * 2048 + n];
      }
    }
    if (bx < 16){
      const int b = bx;
      // hs = h @ Ws_att^T (packed bf16 pairs along k)
      {
        float s0a = 0.f, s1a = 0.f, s0b = 0.f, s1b = 0.f;
        for (int kp = 0; kp < 256; kp++){
          unsigned ua = wst_pk[kp * 512 + tid];
          unsigned ub = wst_pk[kp * 512 + 256 + tid];
          float h0 = hl[2 * kp], h1 = hl[2 * kp + 1];
          s0a += h0 * bf2f((us)ua); s1a += h1 * bf2f((us)(ua >> 16));
          s0b += h0 * bf2f((us)ub); s1b += h1 * bf2f((us)(ub >> 16));
        }
        hs[tid] = s0a + s1a; hs[tid + 256] = s0b + s1b;
      }
      __syncthreads();
      // scores: 2 lanes per s
      {
        const int s = tid >> 1, part = tid & 1;
        const us* ep = enc_proj_bf + (size_t)(b * 128 + s) * 512 + part * 256;
        const float* hsp = hs + part * 256;
        const float* vp  = vl + part * 256;
        float sv = 0.f;
        for (int a = 0; a < 256; a += 8){
          uint4 u = *(const uint4*)(ep + a);
          float e0,e1,e2,e3,e4,e5,e6,e7;
          unpk2(u.x,e0,e1); unpk2(u.y,e2,e3); unpk2(u.z,e4,e5); unpk2(u.w,e6,e7);
          sv += vp[a+0]*tanh_fast(e0+hsp[a+0]) + vp[a+1]*tanh_fast(e1+hsp[a+1])
              + vp[a+2]*tanh_fast(e2+hsp[a+2]) + vp[a+3]*tanh_fast(e3+hsp[a+3])
              + vp[a+4]*tanh_fast(e4+hsp[a+4]) + vp[a+5]*tanh_fast(e5+hsp[a+5])
              + vp[a+6]*tanh_fast(e6+hsp[a+6]) + vp[a+7]*tanh_fast(e7+hsp[a+7]);
        }
        sv += __shfl_xor(sv, 1);
        if (part == 0) att[s] = sv;
      }
      __syncthreads();
      if (tid < 64){
        int slen = src_lens[b];
        float x0 = (tid < slen)      ? att[tid]      : -1e9f;
        float x1 = (tid + 64 < slen) ? att[tid + 64] : -1e9f;
        float m = fmaxf(x0, x1);
        #pragma unroll
        for (int o = 32; o; o >>= 1) m = fmaxf(m, __shfl_xor(m, o));
        float e0 = expf(x0 - m), e1 = expf(x1 - m);
        float ssum = e0 + e1;
        #pragma unroll
        for (int o = 32; o; o >>= 1) ssum += __shfl_xor(ssum, o);
        float inv = 1.0f / ssum;
        att[tid] = e0 * inv; att[tid + 64] = e1 * inv;
      }
      __syncthreads();
      {
        const us* eo = enc_out_bf + (size_t)b * 131072 + 4 * tid;
        float c0 = 0.f, c1 = 0.f, c2 = 0.f, c3 = 0.f;
        for (int s2 = 0; s2 < 128; s2++){
          float a = att[s2];
          uint2 u = *(const uint2*)(eo + (size_t)s2 * 1024);
          float e0,e1,e2,e3; unpk2(u.x,e0,e1); unpk2(u.y,e2,e3);
          c0 += a*e0; c1 += a*e1; c2 += a*e2; c3 += a*e3;
        }
        size_t row = (size_t)t * 16 + b;
        uint2 pk; pk.x = pack2(f2bf(c0), f2bf(c1)); pk.y = pack2(f2bf(c2), f2bf(c3));
        *(uint2*)(hctx + row * 1536 + 512 + 4 * tid) = pk;
      }
    }

    gridbar2(arr, rel, 2 * t + 1, 128);

    // -------- phase B: stage ctx (bf16 copy), ctx@Wctx + g1l -> gates -> cell --------
    for (int u = tid; u < 2048; u += 256){
      int ks = u >> 6, ch = (u >> 4) & 3, b = u & 15;
      *(bf16x8*)Xf[u] = *(const bf16x8*)(hctx + ((size_t)t * 16 + b) * 1536 + 512 + ks * 32 + ch * 8);
    }
    __syncthreads();
    {
      f32x4 acc = {};
      #pragma unroll
      for (int m = 0; m < 8; m++){
        int ks = wv * 8 + m;
        int ua = (ks * 4 + (lane >> 4)) * 16 + (lane & 15);
        acc = __builtin_amdgcn_mfma_f32_16x16x32_bf16(*(const bf16x8*)Xf[ua],
                                                      *(const bf16x8*)Wc[ua], acc, 0, 0, 0);
      }
      P[wv][lane] = acc;
    }
    __syncthreads();
    if (wv == 0){
      f32x4 sum = (P[0][lane] + P[1][lane]) + (P[2][lane] + P[3][lane]);
      int v = lane & 15;
      #pragma unroll
      for (int r = 0; r < 4; r++){
        int b = (lane >> 4) * 4 + r;
        gl[v][b] = sum[r] + g1l[v][b];
      }
    }
    __syncthreads();
    if (tid < 64){
      int b2 = tid & 15, joff = tid >> 4;
      float ig = sigm (gl[joff * 4 + 0][b2]);
      float fg = sigm (gl[joff * 4 + 1][b2]);
      float g2 = tanhf(gl[joff * 4 + 2][b2]);
      float og = sigm (gl[joff * 4 + 3][b2]);
      float cn = fg * creg + ig * g2;
      float hv = og * tanhf(cn);
      creg = cn;
      hctx[((size_t)t * 16 + b2) * 1536 + bx * 4 + joff] = f2bf(hv);
    }
    if (t != 126) gridbar2(arr, rel, 2 * t + 2, 128);
  }
}

extern "C" void kernel_launch(void* const* d_in, const int* in_sizes, int n_in,
                              void* d_out, int out_size, void* d_ws, size_t ws_size,
                              hipStream_t stream)
{
  const int*   src       = (const int*)d_in[0];
  const int*   src_lens  = (const int*)d_in[1];
  const int*   tgt       = (const int*)d_in[2];
  const float* enc_embed = (const float*)d_in[3];
  const float* Wih_f = (const float*)d_in[4];
  const float* Whh_f = (const float*)d_in[5];
  const float* bih_f = (const float*)d_in[6];
  const float* bhh_f = (const float*)d_in[7];
  const float* Wih_b = (const float*)d_in[8];
  const float* Whh_b = (const float*)d_in[9];
  const float* bih_b = (const float*)d_in[10];
  const float* bhh_b = (const float*)d_in[11];
  const float* Wbh = (const float*)d_in[12];
  const float* bbh = (const float*)d_in[13];
  const float* Wbc = (const float*)d_in[14];
  const float* bbc = (const float*)d_in[15];
  const float* Wh_att = (const float*)d_in[16];
  const float* Ws_att = (const float*)d_in[17];
  const float* v_att  = (const float*)d_in[18];
  const float* dec_embed = (const float*)d_in[19];
  const float* Wih_d = (const float*)d_in[20];
  const float* Whh_d = (const float*)d_in[21];
  const float* bih_d = (const float*)d_in[22];
  const float* bhh_d = (const float*)d_in[23];
  const float* Wfc = (const float*)d_in[24];
  const float* bfc = (const float*)d_in[25];
  float* out = (float*)d_out;

  char* base = (char*)d_ws;
  size_t off = 0;
  auto take = [&](size_t bytes) -> char* {
    char* p = base + off;
    off += (bytes + 255) & ~(size_t)255;
    return p;
  };
  us* wfc_bf    = (us*)take((size_t)32000 * 1536 * 2);
  us* emb_e     = (us*)take((size_t)2048 * 512 * 2);
  us* emb_d     = (us*)take((size_t)2048 * 512 * 2);
  us* wihf_bf   = (us*)take((size_t)2048 * 512 * 2);
  us* wihb_bf   = (us*)take((size_t)2048 * 512 * 2);
  us* wihd_bf   = (us*)take((size_t)2048 * 1536 * 2);
  us* whhf_bf   = (us*)take((size_t)2048 * 512 * 2);
  us* whhb_bf   = (us*)take((size_t)2048 * 512 * 2);
  us* whhd_bf   = (us*)take((size_t)2048 * 512 * 2);
  us* whatt_bf  = (us*)take((size_t)512 * 1024 * 2);
  unsigned* wst_pk = (unsigned*)take((size_t)256 * 512 * 4);
  float* gin_f    = (float*)take((size_t)2048 * 2048 * 4);
  float* gin_b    = (float*)take((size_t)2048 * 2048 * 4);
  float* gin_d    = (float*)take((size_t)2048 * 2048 * 4);
  us* enc_out_bf  = (us*)take((size_t)2048 * 1024 * 2);
  us* enc_proj_bf = (us*)take((size_t)2048 * 512 * 2);
  us* hctx        = (us*)take((size_t)2048 * 1536 * 2);
  us* h0_bf       = (us*)take((size_t)16 * 512 * 2);
  float* c_dec    = (float*)take((size_t)16 * 512 * 4);
  float* bias_f = (float*)take(2048 * 4);
  float* bias_b = (float*)take(2048 * 4);
  float* bias_d = (float*)take(2048 * 4);
  unsigned* arrE = (unsigned*)take(128 * 32 * 4);
  unsigned* relE = (unsigned*)take(8 * 32 * 4);
  unsigned* arrD = (unsigned*)take(128 * 32 * 4);
  unsigned* relD = (unsigned*)take(8 * 32 * 4);

  // zeroing: padded dec-embedding rows, hctx (incl. padded logit rows), barrier flags
  hipMemsetAsync(emb_d, 0, (size_t)2048 * 512 * 2, stream);
  hipMemsetAsync(hctx, 0, (size_t)2048 * 1536 * 2, stream);
  hipMemsetAsync(arrE, 0, (128 * 32 + 8 * 32 + 128 * 32 + 8 * 32) * 4 + 3 * 256, stream);

  // weight conversions
  k_f2bf<<<4096, 256, 0, stream>>>((const float4*)Wfc,   (uint2*)wfc_bf,   (long)32000 * 1536 / 4);
  k_f2bf<<<512,  256, 0, stream>>>((const float4*)Wih_f, (uint2*)wihf_bf,  (long)2048 * 512 / 4);
  k_f2bf<<<512,  256, 0, stream>>>((const float4*)Wih_b, (uint2*)wihb_bf,  (long)2048 * 512 / 4);
  k_f2bf<<<1024, 256, 0, stream>>>((const float4*)Wih_d, (uint2*)wihd_bf,  (long)2048 * 1536 / 4);
  k_f2bf<<<512,  256, 0, stream>>>((const float4*)Whh_f, (uint2*)whhf_bf,  (long)2048 * 512 / 4);
  k_f2bf<<<512,  256, 0, stream>>>((const float4*)Whh_b, (uint2*)whhb_bf,  (long)2048 * 512 / 4);
  k_f2bf<<<512,  256, 0, stream>>>((const float4*)Whh_d, (uint2*)whhd_bf,  (long)2048 * 512 / 4);
  k_f2bf<<<512,  256, 0, stream>>>((const float4*)Wh_att,(uint2*)whatt_bf, (long)512 * 1024 / 4);
  k_wst<<<512, 256, 0, stream>>>(Ws_att, wst_pk);
  k_bias3<<<8, 256, 0, stream>>>(bih_f, bhh_f, bias_f, bih_b, bhh_b, bias_b, bih_d, bhh_d, bias_d);

  // embeddings (bf16), rows r = pos*16 + b
  k_embed<<<2048, 128, 0, stream>>>(src, enc_embed, emb_e);
  k_embed<<<2032, 128, 0, stream>>>(tgt, dec_embed, emb_d);

  // input-side gate GEMMs (hoisted out of the scans)
  gemm_bt<0><<<dim3(16, 16), 256, 0, stream>>>(emb_e, 512, wihf_bf, 512,  bias_f, gin_f, 2048, 512, 4096);
  gemm_bt<0><<<dim3(16, 16), 256, 0, stream>>>(emb_e, 512, wihb_bf, 512,  bias_b, gin_b, 2048, 512, 4096);
  gemm_bt<0><<<dim3(16, 16), 256, 0, stream>>>(emb_d, 512, wihd_bf, 1536, bias_d, gin_d, 2048, 512, 4096);

  // encoder: persistent, LDS-resident weights, flag barrier
  enc_persist3<<<128, 256, 0, stream>>>(gin_f, gin_b, whhf_bf, whhb_bf, enc_out_bf, arrE, relE);

  k_h0c0<<<32, 512, 0, stream>>>(enc_out_bf, Wbh, bbh, Wbc, bbc, h0_bf, c_dec);

  // enc_proj (bf16) = enc_out @ Wh_att^T
  gemm_bt<2><<<dim3(4, 16), 256, 0, stream>>>(enc_out_bf, 1024, whatt_bf, 1024, nullptr, enc_proj_bf, 512, 1024, 4096);

  // decoder: persistent, LDS-resident weights, flag barrier
  dec_persist3<<<128, 256, 0, stream>>>(h0_bf, c_dec, wst_pk, v_att, enc_proj_bf, enc_out_bf, src_lens,
                                        gin_d, whhd_bf, wihd_bf, hctx, arrD, relD);

  // one big logits GEMM: [2032,1536] x [32000,1536]^T + bfc -> out (B,T-1,V)
  gemm_bt<1><<<dim3(250, 16), 256, 0, stream>>>(hctx, 1536, wfc_bf, 1536, bfc, out, 32000, 1536, 2032);
}

// Round 5
// 6278.416 us; speedup vs baseline: 3.6745x; 1.0988x over previous
//
#include <hip/hip_runtime.h>

typedef __bf16 bf16x8 __attribute__((ext_vector_type(8)));
typedef float f32x4 __attribute__((ext_vector_type(4)));
typedef unsigned short us;

#define DEV static __device__ __forceinline__

DEV float bf2f(us u){ union { unsigned u; float f; } x; x.u = ((unsigned)u) << 16; return x.f; }
DEV us f2bf(float f){
  union { float f; unsigned u; } x; x.f = f;
  unsigned r = x.u + 0x7fffu + ((x.u >> 16) & 1u);
  return (us)(r >> 16);
}
DEV unsigned pack2(us lo, us hi){ return (unsigned)lo | ((unsigned)hi << 16); }
DEV float sigm(float x){ return 1.0f / (1.0f + expf(-x)); }
DEV float tanh_fast(float x){ float e = __expf(2.0f * x); return 1.0f - 2.0f / (e + 1.0f); }
DEV void unpk2(unsigned u, float& a, float& b){ a = bf2f((us)u); b = bf2f((us)(u >> 16)); }

// ---- flag-based grid barrier: per-block arrival stores (own cacheline each),
// ---- master block (nb-1) aggregates, 8 replicated release lines. No RMW.
DEV void gridbar2(unsigned* arr, unsigned* rel, unsigned ep, int nb){
  __syncthreads();
  const int tid = threadIdx.x, bid = blockIdx.x;
  if (tid == 0){
    __builtin_amdgcn_fence(__ATOMIC_RELEASE, "agent");
    __hip_atomic_store(arr + bid * 32, ep, __ATOMIC_RELAXED, __HIP_MEMORY_SCOPE_AGENT);
  }
  if (bid == nb - 1){
    for (int i = tid; i < nb; i += 256){
      while (__hip_atomic_load(arr + i * 32, __ATOMIC_RELAXED, __HIP_MEMORY_SCOPE_AGENT) < ep)
        __builtin_amdgcn_s_sleep(1);
    }
    __syncthreads();
    __builtin_amdgcn_fence(__ATOMIC_ACQ_REL, "agent");
    if (tid < 8)
      __hip_atomic_store(rel + tid * 32, ep, __ATOMIC_RELAXED, __HIP_MEMORY_SCOPE_AGENT);
  } else if (tid == 0){
    while (__hip_atomic_load(rel + (bid & 7) * 32, __ATOMIC_RELAXED, __HIP_MEMORY_SCOPE_AGENT) < ep)
      __builtin_amdgcn_s_sleep(1);
    __builtin_amdgcn_fence(__ATOMIC_ACQUIRE, "agent");
  }
  __syncthreads();
}

// ---------------- f32 -> bf16 convert ----------------
__global__ void k_f2bf(const float4* __restrict__ in, uint2* __restrict__ out, long n4){
  long stride = (long)gridDim.x * blockDim.x;
  for (long i = (long)blockIdx.x * blockDim.x + threadIdx.x; i < n4; i += stride){
    float4 v = in[i];
    uint2 o; o.x = pack2(f2bf(v.x), f2bf(v.y)); o.y = pack2(f2bf(v.z), f2bf(v.w));
    out[i] = o;
  }
}

__global__ void k_bias3(const float* a0, const float* b0, float* o0,
                        const float* a1, const float* b1, float* o1,
                        const float* a2, const float* b2, float* o2){
  int i = blockIdx.x * 256 + threadIdx.x;   // 2048
  o0[i] = a0[i] + b0[i];
  o1[i] = a1[i] + b1[i];
  o2[i] = a2[i] + b2[i];
}

// embedding gather -> bf16 rows. row r = pos*16 + b ; token = tok[b*128 + pos]
__global__ void k_embed(const int* __restrict__ tok, const float* __restrict__ table,
                        us* __restrict__ out){
  int r = blockIdx.x;
  int b = r & 15, pos = r >> 4;
  int idx = tok[b * 128 + pos];
  float4 v = ((const float4*)(table + (size_t)idx * 512))[threadIdx.x];  // 128 threads
  uint2 o; o.x = pack2(f2bf(v.x), f2bf(v.y)); o.y = pack2(f2bf(v.z), f2bf(v.w));
  ((uint2*)(out + (size_t)r * 512))[threadIdx.x] = o;
}

// ---------------- bf16 MFMA GEMM: C[M,N] = A[M,K] * B[N,K]^T (+bias) ----------------
// MODE 0: f32 C.  MODE 1: logits scatter f32.  MODE 2: bf16 C.
template<int MODE>
__global__ __launch_bounds__(256)
void gemm_bt(const us* __restrict__ A, int lda,
             const us* __restrict__ B, int ldb,
             const float* __restrict__ bias,
             void* __restrict__ Cv, int ldc, int K, int mvalid)
{
  __shared__ __align__(16) us As[128 * 64];
  __shared__ __align__(16) us Bs[128 * 64];
  const int tid  = threadIdx.x;
  const int lane = tid & 63, wid = tid >> 6;
  const int wm = (wid >> 1) * 64, wn = (wid & 1) * 64;
  const us* Ab = A + (size_t)blockIdx.y * 128 * lda;
  const us* Bb = B + (size_t)blockIdx.x * 128 * ldb;

  f32x4 acc[4][4] = {};
  bf16x8 ga[4], gb[4];

  #pragma unroll
  for (int r = 0; r < 4; r++){
    int c = tid + r * 256;
    ga[r] = *(const bf16x8*)(Ab + (size_t)(c >> 3) * lda + (c & 7) * 8);
    gb[r] = *(const bf16x8*)(Bb + (size_t)(c >> 3) * ldb + (c & 7) * 8);
  }
  const int nt = K >> 6;
  for (int t = 0; t < nt; t++){
    #pragma unroll
    for (int r = 0; r < 4; r++){
      int c = tid + r * 256;
      int slot = ((c >> 3) * 8 + ((c & 7) ^ ((c >> 3) & 7))) * 8;
      *(bf16x8*)(As + slot) = ga[r];
      *(bf16x8*)(Bs + slot) = gb[r];
    }
    __syncthreads();
    if (t + 1 < nt){
      int k0 = (t + 1) * 64;
      #pragma unroll
      for (int r = 0; r < 4; r++){
        int c = tid + r * 256;
        ga[r] = *(const bf16x8*)(Ab + (size_t)(c >> 3) * lda + k0 + (c & 7) * 8);
        gb[r] = *(const bf16x8*)(Bb + (size_t)(c >> 3) * ldb + k0 + (c & 7) * 8);
      }
    }
    #pragma unroll
    for (int kk = 0; kk < 2; kk++){
      bf16x8 av[4], bv[4];
      #pragma unroll
      for (int i = 0; i < 4; i++){
        int ra = wm + i * 16 + (lane & 15);
        int ua = (kk * 4 + (lane >> 4)) ^ (ra & 7);
        av[i] = *(const bf16x8*)(As + (ra * 8 + ua) * 8);
        int rb = wn + i * 16 + (lane & 15);
        int ub = (kk * 4 + (lane >> 4)) ^ (rb & 7);
        bv[i] = *(const bf16x8*)(Bs + (rb * 8 + ub) * 8);
      }
      #pragma unroll
      for (int i = 0; i < 4; i++)
        #pragma unroll
        for (int j = 0; j < 4; j++)
          acc[i][j] = __builtin_amdgcn_mfma_f32_16x16x32_bf16(av[i], bv[j], acc[i][j], 0, 0, 0);
    }
    if (t + 1 < nt) __syncthreads();
  }

  const int cb = lane & 15, rb4 = (lane >> 4) * 4;
  #pragma unroll
  for (int i = 0; i < 4; i++){
    #pragma unroll
    for (int j = 0; j < 4; j++){
      #pragma unroll
      for (int r = 0; r < 4; r++){
        int row = blockIdx.y * 128 + wm + i * 16 + rb4 + r;
        int col = blockIdx.x * 128 + wn + j * 16 + cb;
        float v = acc[i][j][r];
        if (bias) v += bias[col];
        if (MODE == 0){
          ((float*)Cv)[(size_t)row * ldc + col] = v;
        } else if (MODE == 2){
          ((us*)Cv)[(size_t)row * ldc + col] = f2bf(v);
        } else {
          if (row < mvalid){
            int tt = row >> 4, b = row & 15;
            ((float*)Cv)[((size_t)b * 127 + tt) * 32000 + col] = v;
          }
        }
      }
    }
  }
}

// =================================================================================
// Persistent encoder v3 (unchanged from round 4)
// =================================================================================
__global__ __launch_bounds__(256)
void enc_persist3(const float* __restrict__ gin_f, const float* __restrict__ gin_b,
                  const us* __restrict__ whhf_bf, const us* __restrict__ whhb_bf,
                  us* __restrict__ enc_out_bf, /* [16][128][1024] bf16 */
                  unsigned* __restrict__ arr, unsigned* __restrict__ rel)
{
  __shared__ __align__(16) us Wt[2][1024][8];
  __shared__ __align__(16) us Hf[2][1024][8];
  __shared__ __align__(16) f32x4 P[2][4][64];
  __shared__ float gl[2][16][17];

  const int bx = blockIdx.x, tid = threadIdx.x;
  const int lane = tid & 63, wv = tid >> 6;

  for (int d = 0; d < 2; d++){
    const us* srcw = d ? whhb_bf : whhf_bf;
    for (int u = tid; u < 1024; u += 256){
      int ks = u >> 6, ch = (u >> 4) & 3, v = u & 15;
      int n = (v & 3) * 512 + bx * 4 + (v >> 2);
      *(bf16x8*)Wt[d][u] = *(const bf16x8*)(srcw + (size_t)n * 512 + ks * 32 + ch * 8);
    }
  }

  float creg = 0.0f;
  const int cd = (tid >> 6) & 1, cb = tid & 15, cj = (tid >> 4) & 3;

  for (int t = 0; t < 128; t++){
    if (t == 0){
      bf16x8 z = {};
      for (int u = tid; u < 2048; u += 256) *(bf16x8*)Hf[u >> 10][u & 1023] = z;
    } else {
      for (int u = tid; u < 2048; u += 256){
        int d = u >> 10, uu = u & 1023;
        int ks = uu >> 6, ch = (uu >> 4) & 3, b = uu & 15;
        int sp = d ? (128 - t) : (t - 1);
        *(bf16x8*)Hf[d][uu] =
          *(const bf16x8*)(enc_out_bf + ((size_t)b * 128 + sp) * 1024 + d * 512 + ks * 32 + ch * 8);
      }
    }
    __syncthreads();
    #pragma unroll
    for (int d = 0; d < 2; d++){
      f32x4 acc = {};
      #pragma unroll
      for (int m = 0; m < 4; m++){
        int ks = wv * 4 + m;
        int ua = (ks * 4 + (lane >> 4)) * 16 + (lane & 15);
        acc = __builtin_amdgcn_mfma_f32_16x16x32_bf16(*(const bf16x8*)Hf[d][ua],
                                                      *(const bf16x8*)Wt[d][ua], acc, 0, 0, 0);
      }
      P[d][wv][lane] = acc;
    }
    __syncthreads();
    if (wv < 2){
      int d = wv;
      f32x4 sum = (P[d][0][lane] + P[d][1][lane]) + (P[d][2][lane] + P[d][3][lane]);
      int v = lane & 15;
      int n = (v & 3) * 512 + bx * 4 + (v >> 2);
      int s_in = d ? (127 - t) : t;
      const float* gg = (d ? gin_b : gin_f) + (size_t)s_in * 16 * 2048 + n;
      #pragma unroll
      for (int r = 0; r < 4; r++){
        int b = (lane >> 4) * 4 + r;
        gl[d][v][b] = sum[r] + gg[(size_t)b * 2048];
      }
    }
    __syncthreads();
    if (tid < 128){
      float ig = sigm (gl[cd][cj * 4 + 0][cb]);
      float fg = sigm (gl[cd][cj * 4 + 1][cb]);
      float g2 = tanhf(gl[cd][cj * 4 + 2][cb]);
      float og = sigm (gl[cd][cj * 4 + 3][cb]);
      float cn = fg * creg + ig * g2;
      float hv = og * tanhf(cn);
      creg = cn;
      int j = bx * 4 + cj;
      int s_in = cd ? (127 - t) : t;
      enc_out_bf[((size_t)cb * 128 + s_in) * 1024 + cd * 512 + j] = f2bf(hv);
    }
    if (t != 127) gridbar2(arr, rel, t + 1, 128);
  }
}

// ---------------- h0/c0 ----------------
__global__ __launch_bounds__(512)
void k_h0c0(const us* __restrict__ enc_out_bf, const float* __restrict__ Wbh, const float* __restrict__ bbh,
            const float* __restrict__ Wbc, const float* __restrict__ bbc,
            us* __restrict__ h0_bf, float* __restrict__ c_dec)
{
  __shared__ float hc[1024];
  int b = blockIdx.x >> 1, which = blockIdx.x & 1;
  int tid = threadIdx.x;
  hc[tid]       = bf2f(enc_out_bf[((size_t)b * 128 + 127) * 1024 + tid]);
  hc[512 + tid] = bf2f(enc_out_bf[((size_t)b * 128 + 0)   * 1024 + 512 + tid]);
  __syncthreads();
  const float* W = which ? Wbc : Wbh;
  float acc = (which ? bbc : bbh)[tid];
  const float* wr = W + (size_t)tid * 1024;
  for (int k = 0; k < 1024; k += 4){
    float4 w = *(const float4*)(wr + k);
    acc += w.x * hc[k] + w.y * hc[k + 1] + w.z * hc[k + 2] + w.w * hc[k + 3];
  }
  float v = tanhf(acc);
  if (which) c_dec[b * 512 + tid] = v;
  else       h0_bf[b * 512 + tid] = f2bf(v);
}

// =================================================================================
// Persistent decoder v4: 128 blocks, 4 parallel phases per step (4 barriers).
// Resident LDS per block: Wh (n-slice of Whh, 16KB), Wc (n-slice of Wctx, 32KB),
// Ws_r (4 rows of Ws_att, 4KB), vl (v_att).
// A: stage h; h@Whh MFMA -> g1l; hs[b][bx*4..+3] -> hs_g.            bar
// B: scores[all b][s=bx] from hs_g + enc_proj + v_att -> scores_g.   bar
// C: softmax (redundant); ctx[all b][k=bx*8..+7] -> hctx row (bf16). bar
// D: stage ctx; ctx@Wc MFMA + g1l -> gates -> cell -> h slice.       bar
// =================================================================================
__global__ __launch_bounds__(256)
void dec_persist4(const us* __restrict__ h0_bf, const float* __restrict__ c_dec0,
                  const float* __restrict__ Ws_att, const float* __restrict__ v_att,
                  const us* __restrict__ enc_proj_bf,
                  const us* __restrict__ enc_out_bf,
                  const int* __restrict__ src_lens,
                  const float* __restrict__ gin_d,
                  const us* __restrict__ whhd_bf, const us* __restrict__ wihd_bf,
                  float* __restrict__ hs_g, float* __restrict__ scores_g,
                  us* __restrict__ hctx,
                  unsigned* __restrict__ arr, unsigned* __restrict__ rel)
{
  __shared__ __align__(16) us Wh[1024][8];     // 16KB resident
  __shared__ __align__(16) us Wc[2048][8];     // 32KB resident
  __shared__ __align__(16) us Ws_r[4][512];    // 4KB resident
  __shared__ __align__(16) us Xf[2048][8];     // 32KB fragments (h / ctx)
  __shared__ __align__(16) f32x4 P[4][64];     // 4KB partials
  __shared__ float g1l[16][17];
  __shared__ float gl[16][17];
  __shared__ float hsl[16][512];               // 32KB (phase B); first 8KB = sc2 (phase C)
  __shared__ float att2[16][128];              // 8KB
  __shared__ float vl[512];
  __shared__ float hsp[4][64];
  __shared__ float wred[4][16];
  __shared__ float mred[16][16];
  __shared__ float mrow[16], irow[16];
  __shared__ float cred[2][128];

  const int bx = blockIdx.x, tid = threadIdx.x;
  const int lane = tid & 63, wv = tid >> 6;
  float* sc2 = &hsl[0][0];                     // 2048 f32 alias (time-disjoint)

  // resident loads
  for (int u = tid; u < 1024; u += 256){
    int ks = u >> 6, ch = (u >> 4) & 3, v = u & 15;
    int n = (v & 3) * 512 + bx * 4 + (v >> 2);
    *(bf16x8*)Wh[u] = *(const bf16x8*)(whhd_bf + (size_t)n * 512 + ks * 32 + ch * 8);
  }
  for (int u = tid; u < 2048; u += 256){
    int ks = u >> 6, ch = (u >> 4) & 3, v = u & 15;
    int n = (v & 3) * 512 + bx * 4 + (v >> 2);
    *(bf16x8*)Wc[u] = *(const bf16x8*)(wihd_bf + (size_t)n * 1536 + 512 + ks * 32 + ch * 8);
  }
  for (int u = tid; u < 2048; u += 256){
    int a = u >> 9, k = u & 511;
    Ws_r[a][k] = f2bf(Ws_att[(size_t)(bx * 4 + a) * 512 + k]);
  }
  for (int u = tid; u < 512; u += 256) vl[u] = v_att[u];

  float creg = 0.0f;                 // tid<64 owns (b=tid&15, j=bx*4+(tid>>4))
  if (tid < 64) creg = c_dec0[(tid & 15) * 512 + bx * 4 + (tid >> 4)];

  for (int t = 0; t < 127; t++){
    const us* hsrc = t ? (hctx + (size_t)(t - 1) * 16 * 1536) : h0_bf;
    const int hstride = t ? 1536 : 512;

    // ================= phase A =================
    for (int u = tid; u < 1024; u += 256){
      int ks = u >> 6, ch = (u >> 4) & 3, b = u & 15;
      *(bf16x8*)Xf[u] = *(const bf16x8*)(hsrc + (size_t)b * hstride + ks * 32 + ch * 8);
    }
    __syncthreads();
    {
      f32x4 acc = {};
      #pragma unroll
      for (int m = 0; m < 4; m++){
        int ks = wv * 4 + m;
        int ua = (ks * 4 + (lane >> 4)) * 16 + (lane & 15);
        acc = __builtin_amdgcn_mfma_f32_16x16x32_bf16(*(const bf16x8*)Xf[ua],
                                                      *(const bf16x8*)Wh[ua], acc, 0, 0, 0);
      }
      P[wv][lane] = acc;
    }
    {  // hs partials (overlaps MFMA latency; reads Xf + resident Ws_r)
      int pr = tid & 63, bq = pr & 15, ai = pr >> 4, kq = tid >> 6;
      const us* wr = Ws_r[ai] + kq * 128;
      float s = 0.f;
      #pragma unroll 8
      for (int k = 0; k < 128; k++){
        int kg = kq * 128 + k;
        s += bf2f(Xf[(kg >> 3) * 16 + bq][kg & 7]) * bf2f(wr[k]);
      }
      hsp[kq][pr] = s;
    }
    __syncthreads();
    if (wv == 0){
      f32x4 sum = (P[0][lane] + P[1][lane]) + (P[2][lane] + P[3][lane]);
      int v = lane & 15;
      int n = (v & 3) * 512 + bx * 4 + (v >> 2);
      #pragma unroll
      for (int r = 0; r < 4; r++){
        int b = (lane >> 4) * 4 + r;
        g1l[v][b] = sum[r] + gin_d[((size_t)t * 16 + b) * 2048 + n];
      }
    }
    if (tid < 64)
      hs_g[(tid & 15) * 512 + bx * 4 + (tid >> 4)] =
        hsp[0][tid] + hsp[1][tid] + hsp[2][tid] + hsp[3][tid];

    gridbar2(arr, rel, 4 * t + 1, 128);

    // ================= phase B: scores for s = bx =================
    for (int u = tid; u < 8192; u += 256) (&hsl[0][0])[u] = hs_g[u];
    __syncthreads();
    {
      int bq = tid & 15, part = tid >> 4;
      const us* ep = enc_proj_bf + ((size_t)bq * 128 + bx) * 512 + part * 32;
      const float* hsb = hsl[bq] + part * 32;
      const float* vp = vl + part * 32;
      float sv = 0.f;
      #pragma unroll
      for (int a = 0; a < 32; a += 8){
        uint4 u4 = *(const uint4*)(ep + a);
        float e0,e1,e2,e3,e4,e5,e6,e7;
        unpk2(u4.x,e0,e1); unpk2(u4.y,e2,e3); unpk2(u4.z,e4,e5); unpk2(u4.w,e6,e7);
        sv += vp[a+0]*tanh_fast(e0+hsb[a+0]) + vp[a+1]*tanh_fast(e1+hsb[a+1])
            + vp[a+2]*tanh_fast(e2+hsb[a+2]) + vp[a+3]*tanh_fast(e3+hsb[a+3])
            + vp[a+4]*tanh_fast(e4+hsb[a+4]) + vp[a+5]*tanh_fast(e5+hsb[a+5])
            + vp[a+6]*tanh_fast(e6+hsb[a+6]) + vp[a+7]*tanh_fast(e7+hsb[a+7]);
      }
      sv += __shfl_xor(sv, 16);
      sv += __shfl_xor(sv, 32);
      if ((tid & 63) < 16) wred[wv][tid & 15] = sv;
    }
    __syncthreads();
    if (tid < 16){
      float sc = wred[0][tid] + wred[1][tid] + wred[2][tid] + wred[3][tid];
      if (bx >= src_lens[tid]) sc = -1e9f;
      scores_g[tid * 128 + bx] = sc;
    }

    gridbar2(arr, rel, 4 * t + 2, 128);

    // ================= phase C: softmax (redundant) + ctx k-slice =================
    for (int u = tid; u < 2048; u += 256) sc2[u] = scores_g[u];
    __syncthreads();
    {
      int bq = tid & 15, part = tid >> 4;
      const float* sb = sc2 + bq * 128 + part * 8;
      float lm = sb[0];
      #pragma unroll
      for (int i = 1; i < 8; i++) lm = fmaxf(lm, sb[i]);
      mred[part][bq] = lm;
    }
    __syncthreads();
    if (tid < 16){
      float m = mred[0][tid];
      #pragma unroll
      for (int i = 1; i < 16; i++) m = fmaxf(m, mred[i][tid]);
      mrow[tid] = m;
    }
    __syncthreads();
    {
      int bq = tid & 15, part = tid >> 4;
      const float* sb = sc2 + bq * 128 + part * 8;
      float m = mrow[bq], se = 0.f;
      #pragma unroll
      for (int i = 0; i < 8; i++) se += __expf(sb[i] - m);
      mred[part][bq] = se;
    }
    __syncthreads();
    if (tid < 16){
      float se = 0.f;
      #pragma unroll
      for (int i = 0; i < 16; i++) se += mred[i][tid];
      irow[tid] = 1.0f / se;
    }
    __syncthreads();
    for (int u = tid; u < 2048; u += 256){
      int bq = u >> 7, s2 = u & 127;
      att2[bq][s2] = __expf(sc2[u] - mrow[bq]) * irow[bq];
    }
    __syncthreads();
    {
      int p2 = tid & 127;
      int bq = p2 >> 3, kk = p2 & 7;
      int half = tid >> 7;
      const us* eo = enc_out_bf + ((size_t)bq * 128 + half * 64) * 1024 + bx * 8 + kk;
      const float* ab = att2[bq] + half * 64;
      float s = 0.f;
      #pragma unroll 8
      for (int s2 = 0; s2 < 64; s2++)
        s += ab[s2] * bf2f(eo[(size_t)s2 * 1024]);
      cred[half][p2] = s;
    }
    __syncthreads();
    if (tid < 128){
      float c = cred[0][tid] + cred[1][tid];
      int bq = tid >> 3, kk = tid & 7;
      hctx[((size_t)t * 16 + bq) * 1536 + 512 + bx * 8 + kk] = f2bf(c);
    }

    gridbar2(arr, rel, 4 * t + 3, 128);

    // ================= phase D: gates + cell =================
    for (int u = tid; u < 2048; u += 256){
      int ks = u >> 6, ch = (u >> 4) & 3, b = u & 15;
      *(bf16x8*)Xf[u] = *(const bf16x8*)(hctx + ((size_t)t * 16 + b) * 1536 + 512 + ks * 32 + ch * 8);
    }
    __syncthreads();
    {
      f32x4 acc = {};
      #pragma unroll
      for (int m = 0; m < 8; m++){
        int ks = wv * 8 + m;
        int ua = (ks * 4 + (lane >> 4)) * 16 + (lane & 15);
        acc = __builtin_amdgcn_mfma_f32_16x16x32_bf16(*(const bf16x8*)Xf[ua],
                                                      *(const bf16x8*)Wc[ua], acc, 0, 0, 0);
      }
      P[wv][lane] = acc;
    }
    __syncthreads();
    if (wv == 0){
      f32x4 sum = (P[0][lane] + P[1][lane]) + (P[2][lane] + P[3][lane]);
      int v = lane & 15;
      #pragma unroll
      for (int r = 0; r < 4; r++){
        int b = (lane >> 4) * 4 + r;
        gl[v][b] = sum[r] + g1l[v][b];
      }
    }
    __syncthreads();
    if (tid < 64){
      int b2 = tid & 15, joff = tid >> 4;
      float ig = sigm (gl[joff * 4 + 0][b2]);
      float fg = sigm (gl[joff * 4 + 1][b2]);
      float g2 = tanhf(gl[joff * 4 + 2][b2]);
      float og = sigm (gl[joff * 4 + 3][b2]);
      float cn = fg * creg + ig * g2;
      float hv = og * tanhf(cn);
      creg = cn;
      hctx[((size_t)t * 16 + b2) * 1536 + bx * 4 + joff] = f2bf(hv);
    }
    if (t != 126) gridbar2(arr, rel, 4 * t + 4, 128);
  }
}

extern "C" void kernel_launch(void* const* d_in, const int* in_sizes, int n_in,
                              void* d_out, int out_size, void* d_ws, size_t ws_size,
                              hipStream_t stream)
{
  const int*   src       = (const int*)d_in[0];
  const int*   src_lens  = (const int*)d_in[1];
  const int*   tgt       = (const int*)d_in[2];
  const float* enc_embed = (const float*)d_in[3];
  const float* Wih_f = (const float*)d_in[4];
  const float* Whh_f = (const float*)d_in[5];
  const float* bih_f = (const float*)d_in[6];
  const float* bhh_f = (const float*)d_in[7];
  const float* Wih_b = (const float*)d_in[8];
  const float* Whh_b = (const float*)d_in[9];
  const float* bih_b = (const float*)d_in[10];
  const float* bhh_b = (const float*)d_in[11];
  const float* Wbh = (const float*)d_in[12];
  const float* bbh = (const float*)d_in[13];
  const float* Wbc = (const float*)d_in[14];
  const float* bbc = (const float*)d_in[15];
  const float* Wh_att = (const float*)d_in[16];
  const float* Ws_att = (const float*)d_in[17];
  const float* v_att  = (const float*)d_in[18];
  const float* dec_embed = (const float*)d_in[19];
  const float* Wih_d = (const float*)d_in[20];
  const float* Whh_d = (const float*)d_in[21];
  const float* bih_d = (const float*)d_in[22];
  const float* bhh_d = (const float*)d_in[23];
  const float* Wfc = (const float*)d_in[24];
  const float* bfc = (const float*)d_in[25];
  float* out = (float*)d_out;

  char* base = (char*)d_ws;
  size_t off = 0;
  auto take = [&](size_t bytes) -> char* {
    char* p = base + off;
    off += (bytes + 255) & ~(size_t)255;
    return p;
  };
  us* wfc_bf    = (us*)take((size_t)32000 * 1536 * 2);
  us* emb_e     = (us*)take((size_t)2048 * 512 * 2);
  us* emb_d     = (us*)take((size_t)2048 * 512 * 2);
  us* wihf_bf   = (us*)take((size_t)2048 * 512 * 2);
  us* wihb_bf   = (us*)take((size_t)2048 * 512 * 2);
  us* wihd_bf   = (us*)take((size_t)2048 * 1536 * 2);
  us* whhf_bf   = (us*)take((size_t)2048 * 512 * 2);
  us* whhb_bf   = (us*)take((size_t)2048 * 512 * 2);
  us* whhd_bf   = (us*)take((size_t)2048 * 512 * 2);
  us* whatt_bf  = (us*)take((size_t)512 * 1024 * 2);
  float* gin_f    = (float*)take((size_t)2048 * 2048 * 4);
  float* gin_b    = (float*)take((size_t)2048 * 2048 * 4);
  float* gin_d    = (float*)take((size_t)2048 * 2048 * 4);
  us* enc_out_bf  = (us*)take((size_t)2048 * 1024 * 2);
  us* enc_proj_bf = (us*)take((size_t)2048 * 512 * 2);
  us* hctx        = (us*)take((size_t)2048 * 1536 * 2);
  us* h0_bf       = (us*)take((size_t)16 * 512 * 2);
  float* c_dec    = (float*)take((size_t)16 * 512 * 4);
  float* hs_g     = (float*)take((size_t)16 * 512 * 4);
  float* scores_g = (float*)take((size_t)2048 * 4);
  float* bias_f = (float*)take(2048 * 4);
  float* bias_b = (float*)take(2048 * 4);
  float* bias_d = (float*)take(2048 * 4);
  unsigned* arrE = (unsigned*)take(128 * 32 * 4);
  unsigned* relE = (unsigned*)take(8 * 32 * 4);
  unsigned* arrD = (unsigned*)take(128 * 32 * 4);
  unsigned* relD = (unsigned*)take(8 * 32 * 4);

  // zeroing: padded dec-embedding rows, hctx (incl. padded logit rows), barrier flags
  hipMemsetAsync(emb_d, 0, (size_t)2048 * 512 * 2, stream);
  hipMemsetAsync(hctx, 0, (size_t)2048 * 1536 * 2, stream);
  hipMemsetAsync(arrE, 0, (128 * 32 + 8 * 32 + 128 * 32 + 8 * 32) * 4 + 3 * 256, stream);

  // weight conversions
  k_f2bf<<<4096, 256, 0, stream>>>((const float4*)Wfc,   (uint2*)wfc_bf,   (long)32000 * 1536 / 4);
  k_f2bf<<<512,  256, 0, stream>>>((const float4*)Wih_f, (uint2*)wihf_bf,  (long)2048 * 512 / 4);
  k_f2bf<<<512,  256, 0, stream>>>((const float4*)Wih_b, (uint2*)wihb_bf,  (long)2048 * 512 / 4);
  k_f2bf<<<1024, 256, 0, stream>>>((const float4*)Wih_d, (uint2*)wihd_bf,  (long)2048 * 1536 / 4);
  k_f2bf<<<512,  256, 0, stream>>>((const float4*)Whh_f, (uint2*)whhf_bf,  (long)2048 * 512 / 4);
  k_f2bf<<<512,  256, 0, stream>>>((const float4*)Whh_b, (uint2*)whhb_bf,  (long)2048 * 512 / 4);
  k_f2bf<<<512,  256, 0, stream>>>((const float4*)Whh_d, (uint2*)whhd_bf,  (long)2048 * 512 / 4);
  k_f2bf<<<512,  256, 0, stream>>>((const float4*)Wh_att,(uint2*)whatt_bf, (long)512 * 1024 / 4);
  k_bias3<<<8, 256, 0, stream>>>(bih_f, bhh_f, bias_f, bih_b, bhh_b, bias_b, bih_d, bhh_d, bias_d);

  // embeddings (bf16), rows r = pos*16 + b
  k_embed<<<2048, 128, 0, stream>>>(src, enc_embed, emb_e);
  k_embed<<<2032, 128, 0, stream>>>(tgt, dec_embed, emb_d);

  // input-side gate GEMMs (hoisted out of the scans)
  gemm_bt<0><<<dim3(16, 16), 256, 0, stream>>>(emb_e, 512, wihf_bf, 512,  bias_f, gin_f, 2048, 512, 4096);
  gemm_bt<0><<<dim3(16, 16), 256, 0, stream>>>(emb_e, 512, wihb_bf, 512,  bias_b, gin_b, 2048, 512, 4096);
  gemm_bt<0><<<dim3(16, 16), 256, 0, stream>>>(emb_d, 512, wihd_bf, 1536, bias_d, gin_d, 2048, 512, 4096);

  // encoder: persistent, LDS-resident weights, flag barrier
  enc_persist3<<<128, 256, 0, stream>>>(gin_f, gin_b, whhf_bf, whhb_bf, enc_out_bf, arrE, relE);

  k_h0c0<<<32, 512, 0, stream>>>(enc_out_bf, Wbh, bbh, Wbc, bbc, h0_bf, c_dec);

  // enc_proj (bf16) = enc_out @ Wh_att^T
  gemm_bt<2><<<dim3(4, 16), 256, 0, stream>>>(enc_out_bf, 1024, whatt_bf, 1024, nullptr, enc_proj_bf, 512, 1024, 4096);

  // decoder: persistent, 4 parallel phases/step
  dec_persist4<<<128, 256, 0, stream>>>(h0_bf, c_dec, Ws_att, v_att, enc_proj_bf, enc_out_bf, src_lens,
                                        gin_d, whhd_bf, wihd_bf, hs_g, scores_g, hctx, arrD, relD);

  // one big logits GEMM: [2032,1536] x [32000,1536]^T + bfc -> out (B,T-1,V)
  gemm_bt<1><<<dim3(250, 16), 256, 0, stream>>>(hctx, 1536, wfc_bf, 1536, bfc, out, 32000, 1536, 2032);
}

// Round 6
// 5490.818 us; speedup vs baseline: 4.2016x; 1.1434x over previous
//
#include <hip/hip_runtime.h>

typedef __bf16 bf16x8 __attribute__((ext_vector_type(8)));
typedef float f32x4 __attribute__((ext_vector_type(4)));
typedef unsigned short us;

#define DEV static __device__ __forceinline__

DEV float bf2f(us u){ union { unsigned u; float f; } x; x.u = ((unsigned)u) << 16; return x.f; }
DEV us f2bf(float f){
  union { float f; unsigned u; } x; x.f = f;
  unsigned r = x.u + 0x7fffu + ((x.u >> 16) & 1u);
  return (us)(r >> 16);
}
DEV unsigned pack2(us lo, us hi){ return (unsigned)lo | ((unsigned)hi << 16); }
DEV float sigm(float x){ return 1.0f / (1.0f + expf(-x)); }
DEV float tanh_fast(float x){ float e = __expf(2.0f * x); return 1.0f - 2.0f / (e + 1.0f); }
DEV void unpk2(unsigned u, float& a, float& b){ a = bf2f((us)u); b = bf2f((us)(u >> 16)); }

// ---- flag-based grid barrier: per-block arrival stores (own cacheline each),
// ---- master block (nb-1) aggregates, 8 replicated release lines. No RMW.
DEV void gridbar2(unsigned* arr, unsigned* rel, unsigned ep, int nb){
  __syncthreads();
  const int tid = threadIdx.x, bid = blockIdx.x;
  if (tid == 0){
    __builtin_amdgcn_fence(__ATOMIC_RELEASE, "agent");
    __hip_atomic_store(arr + bid * 32, ep, __ATOMIC_RELAXED, __HIP_MEMORY_SCOPE_AGENT);
  }
  if (bid == nb - 1){
    for (int i = tid; i < nb; i += 256){
      while (__hip_atomic_load(arr + i * 32, __ATOMIC_RELAXED, __HIP_MEMORY_SCOPE_AGENT) < ep)
        __builtin_amdgcn_s_sleep(1);
    }
    __syncthreads();
    __builtin_amdgcn_fence(__ATOMIC_ACQ_REL, "agent");
    if (tid < 8)
      __hip_atomic_store(rel + tid * 32, ep, __ATOMIC_RELAXED, __HIP_MEMORY_SCOPE_AGENT);
  } else if (tid == 0){
    while (__hip_atomic_load(rel + (bid & 7) * 32, __ATOMIC_RELAXED, __HIP_MEMORY_SCOPE_AGENT) < ep)
      __builtin_amdgcn_s_sleep(1);
    __builtin_amdgcn_fence(__ATOMIC_ACQUIRE, "agent");
  }
  __syncthreads();
}

// ---------------- f32 -> bf16 convert ----------------
__global__ void k_f2bf(const float4* __restrict__ in, uint2* __restrict__ out, long n4){
  long stride = (long)gridDim.x * blockDim.x;
  for (long i = (long)blockIdx.x * blockDim.x + threadIdx.x; i < n4; i += stride){
    float4 v = in[i];
    uint2 o; o.x = pack2(f2bf(v.x), f2bf(v.y)); o.y = pack2(f2bf(v.z), f2bf(v.w));
    out[i] = o;
  }
}

__global__ void k_bias3(const float* a0, const float* b0, float* o0,
                        const float* a1, const float* b1, float* o1,
                        const float* a2, const float* b2, float* o2){
  int i = blockIdx.x * 256 + threadIdx.x;   // 2048
  o0[i] = a0[i] + b0[i];
  o1[i] = a1[i] + b1[i];
  o2[i] = a2[i] + b2[i];
}

// embedding gather -> bf16 rows. row r = pos*16 + b ; token = tok[b*128 + pos]
__global__ void k_embed(const int* __restrict__ tok, const float* __restrict__ table,
                        us* __restrict__ out){
  int r = blockIdx.x;
  int b = r & 15, pos = r >> 4;
  int idx = tok[b * 128 + pos];
  float4 v = ((const float4*)(table + (size_t)idx * 512))[threadIdx.x];  // 128 threads
  uint2 o; o.x = pack2(f2bf(v.x), f2bf(v.y)); o.y = pack2(f2bf(v.z), f2bf(v.w));
  ((uint2*)(out + (size_t)r * 512))[threadIdx.x] = o;
}

// ---------------- bf16 MFMA GEMM: C[M,N] = A[M,K] * B[N,K]^T (+bias) ----------------
// MODE 0: f32 C.  MODE 1: logits scatter f32.  MODE 2: bf16 C.
template<int MODE>
__global__ __launch_bounds__(256)
void gemm_bt(const us* __restrict__ A, int lda,
             const us* __restrict__ B, int ldb,
             const float* __restrict__ bias,
             void* __restrict__ Cv, int ldc, int K, int mvalid)
{
  __shared__ __align__(16) us As[128 * 64];
  __shared__ __align__(16) us Bs[128 * 64];
  const int tid  = threadIdx.x;
  const int lane = tid & 63, wid = tid >> 6;
  const int wm = (wid >> 1) * 64, wn = (wid & 1) * 64;
  const us* Ab = A + (size_t)blockIdx.y * 128 * lda;
  const us* Bb = B + (size_t)blockIdx.x * 128 * ldb;

  f32x4 acc[4][4] = {};
  bf16x8 ga[4], gb[4];

  #pragma unroll
  for (int r = 0; r < 4; r++){
    int c = tid + r * 256;
    ga[r] = *(const bf16x8*)(Ab + (size_t)(c >> 3) * lda + (c & 7) * 8);
    gb[r] = *(const bf16x8*)(Bb + (size_t)(c >> 3) * ldb + (c & 7) * 8);
  }
  const int nt = K >> 6;
  for (int t = 0; t < nt; t++){
    #pragma unroll
    for (int r = 0; r < 4; r++){
      int c = tid + r * 256;
      int slot = ((c >> 3) * 8 + ((c & 7) ^ ((c >> 3) & 7))) * 8;
      *(bf16x8*)(As + slot) = ga[r];
      *(bf16x8*)(Bs + slot) = gb[r];
    }
    __syncthreads();
    if (t + 1 < nt){
      int k0 = (t + 1) * 64;
      #pragma unroll
      for (int r = 0; r < 4; r++){
        int c = tid + r * 256;
        ga[r] = *(const bf16x8*)(Ab + (size_t)(c >> 3) * lda + k0 + (c & 7) * 8);
        gb[r] = *(const bf16x8*)(Bb + (size_t)(c >> 3) * ldb + k0 + (c & 7) * 8);
      }
    }
    #pragma unroll
    for (int kk = 0; kk < 2; kk++){
      bf16x8 av[4], bv[4];
      #pragma unroll
      for (int i = 0; i < 4; i++){
        int ra = wm + i * 16 + (lane & 15);
        int ua = (kk * 4 + (lane >> 4)) ^ (ra & 7);
        av[i] = *(const bf16x8*)(As + (ra * 8 + ua) * 8);
        int rb = wn + i * 16 + (lane & 15);
        int ub = (kk * 4 + (lane >> 4)) ^ (rb & 7);
        bv[i] = *(const bf16x8*)(Bs + (rb * 8 + ub) * 8);
      }
      #pragma unroll
      for (int i = 0; i < 4; i++)
        #pragma unroll
        for (int j = 0; j < 4; j++)
          acc[i][j] = __builtin_amdgcn_mfma_f32_16x16x32_bf16(av[i], bv[j], acc[i][j], 0, 0, 0);
    }
    if (t + 1 < nt) __syncthreads();
  }

  const int cb = lane & 15, rb4 = (lane >> 4) * 4;
  #pragma unroll
  for (int i = 0; i < 4; i++){
    #pragma unroll
    for (int j = 0; j < 4; j++){
      #pragma unroll
      for (int r = 0; r < 4; r++){
        int row = blockIdx.y * 128 + wm + i * 16 + rb4 + r;
        int col = blockIdx.x * 128 + wn + j * 16 + cb;
        float v = acc[i][j][r];
        if (bias) v += bias[col];
        if (MODE == 0){
          ((float*)Cv)[(size_t)row * ldc + col] = v;
        } else if (MODE == 2){
          ((us*)Cv)[(size_t)row * ldc + col] = f2bf(v);
        } else {
          if (row < mvalid){
            int tt = row >> 4, b = row & 15;
            ((float*)Cv)[((size_t)b * 127 + tt) * 32000 + col] = v;
          }
        }
      }
    }
  }
}

// =================================================================================
// Persistent encoder v3 (unchanged)
// =================================================================================
__global__ __launch_bounds__(256)
void enc_persist3(const float* __restrict__ gin_f, const float* __restrict__ gin_b,
                  const us* __restrict__ whhf_bf, const us* __restrict__ whhb_bf,
                  us* __restrict__ enc_out_bf, /* [16][128][1024] bf16 */
                  unsigned* __restrict__ arr, unsigned* __restrict__ rel)
{
  __shared__ __align__(16) us Wt[2][1024][8];
  __shared__ __align__(16) us Hf[2][1024][8];
  __shared__ __align__(16) f32x4 P[2][4][64];
  __shared__ float gl[2][16][17];

  const int bx = blockIdx.x, tid = threadIdx.x;
  const int lane = tid & 63, wv = tid >> 6;

  for (int d = 0; d < 2; d++){
    const us* srcw = d ? whhb_bf : whhf_bf;
    for (int u = tid; u < 1024; u += 256){
      int ks = u >> 6, ch = (u >> 4) & 3, v = u & 15;
      int n = (v & 3) * 512 + bx * 4 + (v >> 2);
      *(bf16x8*)Wt[d][u] = *(const bf16x8*)(srcw + (size_t)n * 512 + ks * 32 + ch * 8);
    }
  }

  float creg = 0.0f;
  const int cd = (tid >> 6) & 1, cb = tid & 15, cj = (tid >> 4) & 3;

  for (int t = 0; t < 128; t++){
    if (t == 0){
      bf16x8 z = {};
      for (int u = tid; u < 2048; u += 256) *(bf16x8*)Hf[u >> 10][u & 1023] = z;
    } else {
      for (int u = tid; u < 2048; u += 256){
        int d = u >> 10, uu = u & 1023;
        int ks = uu >> 6, ch = (uu >> 4) & 3, b = uu & 15;
        int sp = d ? (128 - t) : (t - 1);
        *(bf16x8*)Hf[d][uu] =
          *(const bf16x8*)(enc_out_bf + ((size_t)b * 128 + sp) * 1024 + d * 512 + ks * 32 + ch * 8);
      }
    }
    __syncthreads();
    #pragma unroll
    for (int d = 0; d < 2; d++){
      f32x4 acc = {};
      #pragma unroll
      for (int m = 0; m < 4; m++){
        int ks = wv * 4 + m;
        int ua = (ks * 4 + (lane >> 4)) * 16 + (lane & 15);
        acc = __builtin_amdgcn_mfma_f32_16x16x32_bf16(*(const bf16x8*)Hf[d][ua],
                                                      *(const bf16x8*)Wt[d][ua], acc, 0, 0, 0);
      }
      P[d][wv][lane] = acc;
    }
    __syncthreads();
    if (wv < 2){
      int d = wv;
      f32x4 sum = (P[d][0][lane] + P[d][1][lane]) + (P[d][2][lane] + P[d][3][lane]);
      int v = lane & 15;
      int n = (v & 3) * 512 + bx * 4 + (v >> 2);
      int s_in = d ? (127 - t) : t;
      const float* gg = (d ? gin_b : gin_f) + (size_t)s_in * 16 * 2048 + n;
      #pragma unroll
      for (int r = 0; r < 4; r++){
        int b = (lane >> 4) * 4 + r;
        gl[d][v][b] = sum[r] + gg[(size_t)b * 2048];
      }
    }
    __syncthreads();
    if (tid < 128){
      float ig = sigm (gl[cd][cj * 4 + 0][cb]);
      float fg = sigm (gl[cd][cj * 4 + 1][cb]);
      float g2 = tanhf(gl[cd][cj * 4 + 2][cb]);
      float og = sigm (gl[cd][cj * 4 + 3][cb]);
      float cn = fg * creg + ig * g2;
      float hv = og * tanhf(cn);
      creg = cn;
      int j = bx * 4 + cj;
      int s_in = cd ? (127 - t) : t;
      enc_out_bf[((size_t)cb * 128 + s_in) * 1024 + cd * 512 + j] = f2bf(hv);
    }
    if (t != 127) gridbar2(arr, rel, t + 1, 128);
  }
}

// ---------------- h0/c0 ----------------
__global__ __launch_bounds__(512)
void k_h0c0(const us* __restrict__ enc_out_bf, const float* __restrict__ Wbh, const float* __restrict__ bbh,
            const float* __restrict__ Wbc, const float* __restrict__ bbc,
            us* __restrict__ h0_bf, float* __restrict__ c_dec)
{
  __shared__ float hc[1024];
  int b = blockIdx.x >> 1, which = blockIdx.x & 1;
  int tid = threadIdx.x;
  hc[tid]       = bf2f(enc_out_bf[((size_t)b * 128 + 127) * 1024 + tid]);
  hc[512 + tid] = bf2f(enc_out_bf[((size_t)b * 128 + 0)   * 1024 + 512 + tid]);
  __syncthreads();
  const float* W = which ? Wbc : Wbh;
  float acc = (which ? bbc : bbh)[tid];
  const float* wr = W + (size_t)tid * 1024;
  for (int k = 0; k < 1024; k += 4){
    float4 w = *(const float4*)(wr + k);
    acc += w.x * hc[k] + w.y * hc[k + 1] + w.z * hc[k + 2] + w.w * hc[k + 3];
  }
  float v = tanhf(acc);
  if (which) c_dec[b * 512 + tid] = v;
  else       h0_bf[b * 512 + tid] = f2bf(v);
}

// =================================================================================
// Persistent decoder v5: 128 blocks, 4 phases; ALL per-block-unique read-only data
// LDS-resident (immune to barrier cache invalidation).
// n-slice (A/D): block owns n-rows (v&3)*512 + bx*4 + (v>>2), Wh 16KB + Wc 32KB.
// attention (B/C): bB = bx&15 (batch), sQ = bx>>4 (slice 0..7):
//   B: scores[bB][sQ*16 .. +15] via ep_r[16][512] (16KB resident) + hs row (2KB).
//   C: softmax(bB) + ctx[bB][sQ*128 .. +127] via eo_r[128][128] (32KB resident).
// =================================================================================
__global__ __launch_bounds__(256)
void dec_persist5(const us* __restrict__ h0_bf, const float* __restrict__ c_dec0,
                  const float* __restrict__ Ws_att, const float* __restrict__ v_att,
                  const us* __restrict__ enc_proj_bf,
                  const us* __restrict__ enc_out_bf,
                  const int* __restrict__ src_lens,
                  const float* __restrict__ gin_d,
                  const us* __restrict__ whhd_bf, const us* __restrict__ wihd_bf,
                  float* __restrict__ hs_g, float* __restrict__ scores_g,
                  us* __restrict__ hctx,
                  unsigned* __restrict__ arr, unsigned* __restrict__ rel)
{
  __shared__ __align__(16) us Wh[1024][8];     // 16KB resident (A)
  __shared__ __align__(16) us Wc[2048][8];     // 32KB resident (D)
  __shared__ __align__(16) us Ws_r[4][512];    // 4KB resident (A: hs rows)
  __shared__ __align__(16) us ep_r[16][512];   // 16KB resident (B)
  __shared__ __align__(16) us eo_r[128][128];  // 32KB resident (C)
  __shared__ __align__(16) us Xf[2048][8];     // 32KB fragments (A: h, D: ctx)
  __shared__ __align__(16) f32x4 P[4][64];     // 4KB partials
  __shared__ float g1l[16][17];
  __shared__ float gl[16][17];
  __shared__ float vl[512];
  __shared__ float hsp[4][64];
  __shared__ float hs_b[512];
  __shared__ float att[128];
  __shared__ float cred[2][128];
  __shared__ float sred[8];

  const int bx = blockIdx.x, tid = threadIdx.x;
  const int lane = tid & 63, wv = tid >> 6;
  const int bB = bx & 15, sQ = bx >> 4;

  // ---- resident loads (once) ----
  for (int u = tid; u < 1024; u += 256){
    int ks = u >> 6, ch = (u >> 4) & 3, v = u & 15;
    int n = (v & 3) * 512 + bx * 4 + (v >> 2);
    *(bf16x8*)Wh[u] = *(const bf16x8*)(whhd_bf + (size_t)n * 512 + ks * 32 + ch * 8);
  }
  for (int u = tid; u < 2048; u += 256){
    int ks = u >> 6, ch = (u >> 4) & 3, v = u & 15;
    int n = (v & 3) * 512 + bx * 4 + (v >> 2);
    *(bf16x8*)Wc[u] = *(const bf16x8*)(wihd_bf + (size_t)n * 1536 + 512 + ks * 32 + ch * 8);
  }
  for (int u = tid; u < 2048; u += 256){
    int a = u >> 9, k = u & 511;
    Ws_r[a][k] = f2bf(Ws_att[(size_t)(bx * 4 + a) * 512 + k]);
  }
  for (int u = tid; u < 1024; u += 256){      // ep_r: s = sQ*16+si
    int si = u >> 6, a8 = (u & 63) * 8;
    *(bf16x8*)&ep_r[si][a8] =
      *(const bf16x8*)(enc_proj_bf + ((size_t)bB * 128 + sQ * 16 + si) * 512 + a8);
  }
  for (int u = tid; u < 2048; u += 256){      // eo_r: k = sQ*128+kk
    int s = u >> 4, k8 = (u & 15) * 8;
    *(bf16x8*)&eo_r[s][k8] =
      *(const bf16x8*)(enc_out_bf + ((size_t)bB * 128 + s) * 1024 + sQ * 128 + k8);
  }
  for (int u = tid; u < 512; u += 256) vl[u] = v_att[u];
  const int slen = src_lens[bB];

  float creg = 0.0f;                 // tid<64 owns (b=tid&15, j=bx*4+(tid>>4))
  if (tid < 64) creg = c_dec0[(tid & 15) * 512 + bx * 4 + (tid >> 4)];

  for (int t = 0; t < 127; t++){
    const us* hsrc = t ? (hctx + (size_t)(t - 1) * 16 * 1536) : h0_bf;
    const int hstride = t ? 1536 : 512;

    // ================= phase A: h@Whh -> g1l ; hs slice -> hs_g =================
    for (int u = tid; u < 1024; u += 256){
      int ks = u >> 6, ch = (u >> 4) & 3, b = u & 15;
      *(bf16x8*)Xf[u] = *(const bf16x8*)(hsrc + (size_t)b * hstride + ks * 32 + ch * 8);
    }
    __syncthreads();
    {
      f32x4 acc = {};
      #pragma unroll
      for (int m = 0; m < 4; m++){
        int ks = wv * 4 + m;
        int ua = (ks * 4 + (lane >> 4)) * 16 + (lane & 15);
        acc = __builtin_amdgcn_mfma_f32_16x16x32_bf16(*(const bf16x8*)Xf[ua],
                                                      *(const bf16x8*)Wh[ua], acc, 0, 0, 0);
      }
      P[wv][lane] = acc;
    }
    {  // hs partials: a-rows bx*4..+3
      int pr = tid & 63, bq = pr & 15, ai = pr >> 4, kq = tid >> 6;
      const us* wr = Ws_r[ai] + kq * 128;
      float s = 0.f;
      #pragma unroll 8
      for (int k = 0; k < 128; k++){
        int kg = kq * 128 + k;
        s += bf2f(Xf[(kg >> 3) * 16 + bq][kg & 7]) * bf2f(wr[k]);
      }
      hsp[kq][pr] = s;
    }
    __syncthreads();
    if (wv == 0){
      f32x4 sum = (P[0][lane] + P[1][lane]) + (P[2][lane] + P[3][lane]);
      int v = lane & 15;
      int n = (v & 3) * 512 + bx * 4 + (v >> 2);
      #pragma unroll
      for (int r = 0; r < 4; r++){
        int b = (lane >> 4) * 4 + r;
        g1l[v][b] = sum[r] + gin_d[((size_t)t * 16 + b) * 2048 + n];
      }
    }
    if (tid < 64)
      hs_g[(tid & 15) * 512 + bx * 4 + (tid >> 4)] =
        hsp[0][tid] + hsp[1][tid] + hsp[2][tid] + hsp[3][tid];

    gridbar2(arr, rel, 4 * t + 1, 128);

    // ================= phase B: scores[bB][sQ*16..+15] =================
    for (int u = tid; u < 512; u += 256) hs_b[u] = hs_g[bB * 512 + u];
    __syncthreads();
    {
      int si = tid >> 4, part = tid & 15;     // a-range part*32..+31
      const us* er = ep_r[si] + part * 32;
      const float* hb = hs_b + part * 32;
      const float* vp = vl + part * 32;
      float sv = 0.f;
      #pragma unroll
      for (int a = 0; a < 32; a += 8){
        uint4 u4 = *(const uint4*)(er + a);
        float e0,e1,e2,e3,e4,e5,e6,e7;
        unpk2(u4.x,e0,e1); unpk2(u4.y,e2,e3); unpk2(u4.z,e4,e5); unpk2(u4.w,e6,e7);
        sv += vp[a+0]*tanh_fast(e0+hb[a+0]) + vp[a+1]*tanh_fast(e1+hb[a+1])
            + vp[a+2]*tanh_fast(e2+hb[a+2]) + vp[a+3]*tanh_fast(e3+hb[a+3])
            + vp[a+4]*tanh_fast(e4+hb[a+4]) + vp[a+5]*tanh_fast(e5+hb[a+5])
            + vp[a+6]*tanh_fast(e6+hb[a+6]) + vp[a+7]*tanh_fast(e7+hb[a+7]);
      }
      sv += __shfl_xor(sv, 1);
      sv += __shfl_xor(sv, 2);
      sv += __shfl_xor(sv, 4);
      sv += __shfl_xor(sv, 8);
      if (part == 0){
        int s = sQ * 16 + si;
        scores_g[bB * 128 + s] = (s < slen) ? sv : -1e9f;
      }
    }

    gridbar2(arr, rel, 4 * t + 2, 128);

    // ================= phase C: softmax(bB) + ctx[bB][sQ*128..+127] =================
    {
      float x = (tid < 128) ? scores_g[bB * 128 + tid] : -3e38f;
      float m = x;
      #pragma unroll
      for (int o = 32; o; o >>= 1) m = fmaxf(m, __shfl_xor(m, o));
      if (lane == 0) sred[wv] = m;
      __syncthreads();
      m = fmaxf(fmaxf(sred[0], sred[1]), fmaxf(sred[2], sred[3]));
      float e = (tid < 128) ? __expf(x - m) : 0.f;
      float ss = e;
      #pragma unroll
      for (int o = 32; o; o >>= 1) ss += __shfl_xor(ss, o);
      if (lane == 0) sred[4 + wv] = ss;
      __syncthreads();
      float inv = 1.0f / (sred[4] + sred[5] + sred[6] + sred[7]);
      if (tid < 128) att[tid] = e * inv;
    }
    __syncthreads();
    {
      int kk = tid & 127, half = tid >> 7;
      const float* ab = att + half * 64;
      const us* er = &eo_r[half * 64][kk];
      float s = 0.f;
      #pragma unroll 8
      for (int s2 = 0; s2 < 64; s2++)
        s += ab[s2] * bf2f(er[(size_t)s2 * 128]);
      cred[half][kk] = s;
    }
    __syncthreads();
    if (tid < 64){
      int kk2 = tid * 2;
      float c0 = cred[0][kk2]     + cred[1][kk2];
      float c1 = cred[0][kk2 + 1] + cred[1][kk2 + 1];
      *(unsigned*)(hctx + ((size_t)t * 16 + bB) * 1536 + 512 + sQ * 128 + kk2) =
        pack2(f2bf(c0), f2bf(c1));
    }

    gridbar2(arr, rel, 4 * t + 3, 128);

    // ================= phase D: ctx@Wc + g1l -> gates -> cell =================
    for (int u = tid; u < 2048; u += 256){
      int ks = u >> 6, ch = (u >> 4) & 3, b = u & 15;
      *(bf16x8*)Xf[u] = *(const bf16x8*)(hctx + ((size_t)t * 16 + b) * 1536 + 512 + ks * 32 + ch * 8);
    }
    __syncthreads();
    {
      f32x4 acc = {};
      #pragma unroll
      for (int m = 0; m < 8; m++){
        int ks = wv * 8 + m;
        int ua = (ks * 4 + (lane >> 4)) * 16 + (lane & 15);
        acc = __builtin_amdgcn_mfma_f32_16x16x32_bf16(*(const bf16x8*)Xf[ua],
                                                      *(const bf16x8*)Wc[ua], acc, 0, 0, 0);
      }
      P[wv][lane] = acc;
    }
    __syncthreads();
    if (wv == 0){
      f32x4 sum = (P[0][lane] + P[1][lane]) + (P[2][lane] + P[3][lane]);
      int v = lane & 15;
      #pragma unroll
      for (int r = 0; r < 4; r++){
        int b = (lane >> 4) * 4 + r;
        gl[v][b] = sum[r] + g1l[v][b];
      }
    }
    __syncthreads();
    if (tid < 64){
      int b2 = tid & 15, joff = tid >> 4;
      float ig = sigm (gl[joff * 4 + 0][b2]);
      float fg = sigm (gl[joff * 4 + 1][b2]);
      float g2 = tanhf(gl[joff * 4 + 2][b2]);
      float og = sigm (gl[joff * 4 + 3][b2]);
      float cn = fg * creg + ig * g2;
      float hv = og * tanhf(cn);
      creg = cn;
      hctx[((size_t)t * 16 + b2) * 1536 + bx * 4 + joff] = f2bf(hv);
    }
    if (t != 126) gridbar2(arr, rel, 4 * t + 4, 128);
  }
}

extern "C" void kernel_launch(void* const* d_in, const int* in_sizes, int n_in,
                              void* d_out, int out_size, void* d_ws, size_t ws_size,
                              hipStream_t stream)
{
  const int*   src       = (const int*)d_in[0];
  const int*   src_lens  = (const int*)d_in[1];
  const int*   tgt       = (const int*)d_in[2];
  const float* enc_embed = (const float*)d_in[3];
  const float* Wih_f = (const float*)d_in[4];
  const float* Whh_f = (const float*)d_in[5];
  const float* bih_f = (const float*)d_in[6];
  const float* bhh_f = (const float*)d_in[7];
  const float* Wih_b = (const float*)d_in[8];
  const float* Whh_b = (const float*)d_in[9];
  const float* bih_b = (const float*)d_in[10];
  const float* bhh_b = (const float*)d_in[11];
  const float* Wbh = (const float*)d_in[12];
  const float* bbh = (const float*)d_in[13];
  const float* Wbc = (const float*)d_in[14];
  const float* bbc = (const float*)d_in[15];
  const float* Wh_att = (const float*)d_in[16];
  const float* Ws_att = (const float*)d_in[17];
  const float* v_att  = (const float*)d_in[18];
  const float* dec_embed = (const float*)d_in[19];
  const float* Wih_d = (const float*)d_in[20];
  const float* Whh_d = (const float*)d_in[21];
  const float* bih_d = (const float*)d_in[22];
  const float* bhh_d = (const float*)d_in[23];
  const float* Wfc = (const float*)d_in[24];
  const float* bfc = (const float*)d_in[25];
  float* out = (float*)d_out;

  char* base = (char*)d_ws;
  size_t off = 0;
  auto take = [&](size_t bytes) -> char* {
    char* p = base + off;
    off += (bytes + 255) & ~(size_t)255;
    return p;
  };
  us* wfc_bf    = (us*)take((size_t)32000 * 1536 * 2);
  us* emb_e     = (us*)take((size_t)2048 * 512 * 2);
  us* emb_d     = (us*)take((size_t)2048 * 512 * 2);
  us* wihf_bf   = (us*)take((size_t)2048 * 512 * 2);
  us* wihb_bf   = (us*)take((size_t)2048 * 512 * 2);
  us* wihd_bf   = (us*)take((size_t)2048 * 1536 * 2);
  us* whhf_bf   = (us*)take((size_t)2048 * 512 * 2);
  us* whhb_bf   = (us*)take((size_t)2048 * 512 * 2);
  us* whhd_bf   = (us*)take((size_t)2048 * 512 * 2);
  us* whatt_bf  = (us*)take((size_t)512 * 1024 * 2);
  float* gin_f    = (float*)take((size_t)2048 * 2048 * 4);
  float* gin_b    = (float*)take((size_t)2048 * 2048 * 4);
  float* gin_d    = (float*)take((size_t)2048 * 2048 * 4);
  us* enc_out_bf  = (us*)take((size_t)2048 * 1024 * 2);
  us* enc_proj_bf = (us*)take((size_t)2048 * 512 * 2);
  us* hctx        = (us*)take((size_t)2048 * 1536 * 2);
  us* h0_bf       = (us*)take((size_t)16 * 512 * 2);
  float* c_dec    = (float*)take((size_t)16 * 512 * 4);
  float* hs_g     = (float*)take((size_t)16 * 512 * 4);
  float* scores_g = (float*)take((size_t)2048 * 4);
  float* bias_f = (float*)take(2048 * 4);
  float* bias_b = (float*)take(2048 * 4);
  float* bias_d = (float*)take(2048 * 4);
  unsigned* arrE = (unsigned*)take(128 * 32 * 4);
  unsigned* relE = (unsigned*)take(8 * 32 * 4);
  unsigned* arrD = (unsigned*)take(128 * 32 * 4);
  unsigned* relD = (unsigned*)take(8 * 32 * 4);

  // zeroing: padded dec-embedding rows, hctx (incl. padded logit rows), barrier flags
  hipMemsetAsync(emb_d, 0, (size_t)2048 * 512 * 2, stream);
  hipMemsetAsync(hctx, 0, (size_t)2048 * 1536 * 2, stream);
  hipMemsetAsync(arrE, 0, (128 * 32 + 8 * 32 + 128 * 32 + 8 * 32) * 4 + 3 * 256, stream);

  // weight conversions
  k_f2bf<<<4096, 256, 0, stream>>>((const float4*)Wfc,   (uint2*)wfc_bf,   (long)32000 * 1536 / 4);
  k_f2bf<<<512,  256, 0, stream>>>((const float4*)Wih_f, (uint2*)wihf_bf,  (long)2048 * 512 / 4);
  k_f2bf<<<512,  256, 0, stream>>>((const float4*)Wih_b, (uint2*)wihb_bf,  (long)2048 * 512 / 4);
  k_f2bf<<<1024, 256, 0, stream>>>((const float4*)Wih_d, (uint2*)wihd_bf,  (long)2048 * 1536 / 4);
  k_f2bf<<<512,  256, 0, stream>>>((const float4*)Whh_f, (uint2*)whhf_bf,  (long)2048 * 512 / 4);
  k_f2bf<<<512,  256, 0, stream>>>((const float4*)Whh_b, (uint2*)whhb_bf,  (long)2048 * 512 / 4);
  k_f2bf<<<512,  256, 0, stream>>>((const float4*)Whh_d, (uint2*)whhd_bf,  (long)2048 * 512 / 4);
  k_f2bf<<<512,  256, 0, stream>>>((const float4*)Wh_att,(uint2*)whatt_bf, (long)512 * 1024 / 4);
  k_bias3<<<8, 256, 0, stream>>>(bih_f, bhh_f, bias_f, bih_b, bhh_b, bias_b, bih_d, bhh_d, bias_d);

  // embeddings (bf16), rows r = pos*16 + b
  k_embed<<<2048, 128, 0, stream>>>(src, enc_embed, emb_e);
  k_embed<<<2032, 128, 0, stream>>>(tgt, dec_embed, emb_d);

  // input-side gate GEMMs (hoisted out of the scans)
  gemm_bt<0><<<dim3(16, 16), 256, 0, stream>>>(emb_e, 512, wihf_bf, 512,  bias_f, gin_f, 2048, 512, 4096);
  gemm_bt<0><<<dim3(16, 16), 256, 0, stream>>>(emb_e, 512, wihb_bf, 512,  bias_b, gin_b, 2048, 512, 4096);
  gemm_bt<0><<<dim3(16, 16), 256, 0, stream>>>(emb_d, 512, wihd_bf, 1536, bias_d, gin_d, 2048, 512, 4096);

  // encoder: persistent, LDS-resident weights, flag barrier
  enc_persist3<<<128, 256, 0, stream>>>(gin_f, gin_b, whhf_bf, whhb_bf, enc_out_bf, arrE, relE);

  k_h0c0<<<32, 512, 0, stream>>>(enc_out_bf, Wbh, bbh, Wbc, bbc, h0_bf, c_dec);

  // enc_proj (bf16) = enc_out @ Wh_att^T
  gemm_bt<2><<<dim3(4, 16), 256, 0, stream>>>(enc_out_bf, 1024, whatt_bf, 1024, nullptr, enc_proj_bf, 512, 1024, 4096);

  // decoder: persistent, LDS-resident everything
  dec_persist5<<<128, 256, 0, stream>>>(h0_bf, c_dec, Ws_att, v_att, enc_proj_bf, enc_out_bf, src_lens,
                                        gin_d, whhd_bf, wihd_bf, hs_g, scores_g, hctx, arrD, relD);

  // one big logits GEMM: [2032,1536] x [32000,1536]^T + bfc -> out (B,T-1,V)
  gemm_bt<1><<<dim3(250, 16), 256, 0, stream>>>(hctx, 1536, wfc_bf, 1536, bfc, out, 32000, 1536, 2032);
}

// Round 7
// 3820.934 us; speedup vs baseline: 6.0378x; 1.4370x over previous
//
#include <hip/hip_runtime.h>

typedef __bf16 bf16x8 __attribute__((ext_vector_type(8)));
typedef float f32x4 __attribute__((ext_vector_type(4)));
typedef unsigned short us;
typedef unsigned long long ull;

#define DEV static __device__ __forceinline__

DEV float bf2f(us u){ union { unsigned u; float f; } x; x.u = ((unsigned)u) << 16; return x.f; }
DEV us f2bf(float f){
  union { float f; unsigned u; } x; x.f = f;
  unsigned r = x.u + 0x7fffu + ((x.u >> 16) & 1u);
  return (us)(r >> 16);
}
DEV unsigned pack2(us lo, us hi){ return (unsigned)lo | ((unsigned)hi << 16); }
DEV float sigm(float x){ return 1.0f / (1.0f + expf(-x)); }
DEV float tanh_fast(float x){ float e = __expf(2.0f * x); return 1.0f - 2.0f / (e + 1.0f); }
DEV void unpk2(unsigned u, float& a, float& b){ a = bf2f((us)u); b = bf2f((us)(u >> 16)); }

// ---- coherent (L2-bypassing, agent-scope) accesses for cross-block data ----
DEV unsigned ld4v(const unsigned* p){ return __hip_atomic_load(p, __ATOMIC_RELAXED, __HIP_MEMORY_SCOPE_AGENT); }
DEV ull ld8v(const void* p){ return __hip_atomic_load((const ull*)p, __ATOMIC_RELAXED, __HIP_MEMORY_SCOPE_AGENT); }
DEV void st4v(unsigned* p, unsigned v){ __hip_atomic_store(p, v, __ATOMIC_RELAXED, __HIP_MEMORY_SCOPE_AGENT); }

// ---- fence-free all-to-all grid barrier (128 blocks) ----
// __syncthreads drains each wave's vmcnt (sc1 stores visible at coherence point);
// RELEASE flag store orders after; readers use sc1 loads so no acquire-invalidate needed.
DEV void gridbar3(unsigned* arr, unsigned ep){
  __syncthreads();
  if (threadIdx.x == 0)
    __hip_atomic_store(arr + (size_t)blockIdx.x * 16, ep, __ATOMIC_RELEASE, __HIP_MEMORY_SCOPE_AGENT);
  if (threadIdx.x < 128){
    while (__hip_atomic_load(arr + (size_t)threadIdx.x * 16, __ATOMIC_RELAXED, __HIP_MEMORY_SCOPE_AGENT) < ep)
      __builtin_amdgcn_s_sleep(4);
  }
  __syncthreads();
}

// ---------------- f32 -> bf16 convert ----------------
__global__ void k_f2bf(const float4* __restrict__ in, uint2* __restrict__ out, long n4){
  long stride = (long)gridDim.x * blockDim.x;
  for (long i = (long)blockIdx.x * blockDim.x + threadIdx.x; i < n4; i += stride){
    float4 v = in[i];
    uint2 o; o.x = pack2(f2bf(v.x), f2bf(v.y)); o.y = pack2(f2bf(v.z), f2bf(v.w));
    out[i] = o;
  }
}

__global__ void k_bias3(const float* a0, const float* b0, float* o0,
                        const float* a1, const float* b1, float* o1,
                        const float* a2, const float* b2, float* o2){
  int i = blockIdx.x * 256 + threadIdx.x;   // 2048
  o0[i] = a0[i] + b0[i];
  o1[i] = a1[i] + b1[i];
  o2[i] = a2[i] + b2[i];
}

// embedding gather -> bf16 rows. row r = pos*16 + b ; token = tok[b*128 + pos]
__global__ void k_embed(const int* __restrict__ tok, const float* __restrict__ table,
                        us* __restrict__ out){
  int r = blockIdx.x;
  int b = r & 15, pos = r >> 4;
  int idx = tok[b * 128 + pos];
  float4 v = ((const float4*)(table + (size_t)idx * 512))[threadIdx.x];  // 128 threads
  uint2 o; o.x = pack2(f2bf(v.x), f2bf(v.y)); o.y = pack2(f2bf(v.z), f2bf(v.w));
  ((uint2*)(out + (size_t)r * 512))[threadIdx.x] = o;
}

// ---------------- bf16 MFMA GEMM: C[M,N] = A[M,K] * B[N,K]^T (+bias) ----------------
// MODE 0: f32 C.  MODE 1: logits scatter f32.  MODE 2: bf16 C.
template<int MODE>
__global__ __launch_bounds__(256)
void gemm_bt(const us* __restrict__ A, int lda,
             const us* __restrict__ B, int ldb,
             const float* __restrict__ bias,
             void* __restrict__ Cv, int ldc, int K, int mvalid)
{
  __shared__ __align__(16) us As[128 * 64];
  __shared__ __align__(16) us Bs[128 * 64];
  const int tid  = threadIdx.x;
  const int lane = tid & 63, wid = tid >> 6;
  const int wm = (wid >> 1) * 64, wn = (wid & 1) * 64;
  const us* Ab = A + (size_t)blockIdx.y * 128 * lda;
  const us* Bb = B + (size_t)blockIdx.x * 128 * ldb;

  f32x4 acc[4][4] = {};
  bf16x8 ga[4], gb[4];

  #pragma unroll
  for (int r = 0; r < 4; r++){
    int c = tid + r * 256;
    ga[r] = *(const bf16x8*)(Ab + (size_t)(c >> 3) * lda + (c & 7) * 8);
    gb[r] = *(const bf16x8*)(Bb + (size_t)(c >> 3) * ldb + (c & 7) * 8);
  }
  const int nt = K >> 6;
  for (int t = 0; t < nt; t++){
    #pragma unroll
    for (int r = 0; r < 4; r++){
      int c = tid + r * 256;
      int slot = ((c >> 3) * 8 + ((c & 7) ^ ((c >> 3) & 7))) * 8;
      *(bf16x8*)(As + slot) = ga[r];
      *(bf16x8*)(Bs + slot) = gb[r];
    }
    __syncthreads();
    if (t + 1 < nt){
      int k0 = (t + 1) * 64;
      #pragma unroll
      for (int r = 0; r < 4; r++){
        int c = tid + r * 256;
        ga[r] = *(const bf16x8*)(Ab + (size_t)(c >> 3) * lda + k0 + (c & 7) * 8);
        gb[r] = *(const bf16x8*)(Bb + (size_t)(c >> 3) * ldb + k0 + (c & 7) * 8);
      }
    }
    #pragma unroll
    for (int kk = 0; kk < 2; kk++){
      bf16x8 av[4], bv[4];
      #pragma unroll
      for (int i = 0; i < 4; i++){
        int ra = wm + i * 16 + (lane & 15);
        int ua = (kk * 4 + (lane >> 4)) ^ (ra & 7);
        av[i] = *(const bf16x8*)(As + (ra * 8 + ua) * 8);
        int rb = wn + i * 16 + (lane & 15);
        int ub = (kk * 4 + (lane >> 4)) ^ (rb & 7);
        bv[i] = *(const bf16x8*)(Bs + (rb * 8 + ub) * 8);
      }
      #pragma unroll
      for (int i = 0; i < 4; i++)
        #pragma unroll
        for (int j = 0; j < 4; j++)
          acc[i][j] = __builtin_amdgcn_mfma_f32_16x16x32_bf16(av[i], bv[j], acc[i][j], 0, 0, 0);
    }
    if (t + 1 < nt) __syncthreads();
  }

  const int cb = lane & 15, rb4 = (lane >> 4) * 4;
  #pragma unroll
  for (int i = 0; i < 4; i++){
    #pragma unroll
    for (int j = 0; j < 4; j++){
      #pragma unroll
      for (int r = 0; r < 4; r++){
        int row = blockIdx.y * 128 + wm + i * 16 + rb4 + r;
        int col = blockIdx.x * 128 + wn + j * 16 + cb;
        float v = acc[i][j][r];
        if (bias) v += bias[col];
        if (MODE == 0){
          ((float*)Cv)[(size_t)row * ldc + col] = v;
        } else if (MODE == 2){
          ((us*)Cv)[(size_t)row * ldc + col] = f2bf(v);
        } else {
          if (row < mvalid){
            int tt = row >> 4, b = row & 15;
            ((float*)Cv)[((size_t)b * 127 + tt) * 32000 + col] = v;
          }
        }
      }
    }
  }
}

// =================================================================================
// Persistent encoder v4: fence-free. h exchange via sc1 coalesced loads into
// padded row-major LDS; h writes via packed 4B sc1 stores. 1 barrier/step.
// =================================================================================
__global__ __launch_bounds__(256)
void enc_persist4(const float* __restrict__ gin_f, const float* __restrict__ gin_b,
                  const us* __restrict__ whhf_bf, const us* __restrict__ whhb_bf,
                  us* __restrict__ enc_out_bf, /* [16][128][1024] bf16 */
                  unsigned* __restrict__ arr)
{
  __shared__ __align__(16) us Wt[2][1024][8];   // 32KB resident weights
  __shared__ __align__(16) us Hrow[2][16][520]; // 33KB padded row-major h
  __shared__ __align__(16) f32x4 P[2][4][64];
  __shared__ float gl[2][16][17];
  __shared__ float hvout[2][16][4];

  const int bx = blockIdx.x, tid = threadIdx.x;
  const int lane = tid & 63, wv = tid >> 6;

  for (int d = 0; d < 2; d++){
    const us* srcw = d ? whhb_bf : whhf_bf;
    for (int u = tid; u < 1024; u += 256){
      int ks = u >> 6, ch = (u >> 4) & 3, v = u & 15;
      int n = (v & 3) * 512 + bx * 4 + (v >> 2);
      *(bf16x8*)Wt[d][u] = *(const bf16x8*)(srcw + (size_t)n * 512 + ks * 32 + ch * 8);
    }
  }

  float creg = 0.0f;
  const int cd = (tid >> 6) & 1, cb = tid & 15, cj = (tid >> 4) & 3;

  for (int t = 0; t < 128; t++){
    if (t == 0){
      #pragma unroll
      for (int r = 0; r < 8; r++){
        int u = tid + r * 256;                 // u = d*1024 + b*64 + s16
        int d = u >> 10, b = (u >> 6) & 15, s16 = u & 63;
        *(ull*)&Hrow[d][b][s16 * 8]     = 0ull;
        *(ull*)&Hrow[d][b][s16 * 8 + 4] = 0ull;
      }
    } else {
      #pragma unroll
      for (int r = 0; r < 8; r++){
        int u = tid + r * 256;
        int d = u >> 10, b = (u >> 6) & 15, s16 = u & 63;
        int sp = d ? (128 - t) : (t - 1);
        const us* s = enc_out_bf + ((size_t)b * 128 + sp) * 1024 + d * 512 + s16 * 8;
        ull lo = ld8v(s), hi = ld8v(s + 4);
        *(ull*)&Hrow[d][b][s16 * 8]     = lo;
        *(ull*)&Hrow[d][b][s16 * 8 + 4] = hi;
      }
    }
    __syncthreads();
    #pragma unroll
    for (int d = 0; d < 2; d++){
      f32x4 acc = {};
      #pragma unroll
      for (int m = 0; m < 4; m++){
        int ks = wv * 4 + m;
        int ch = lane >> 4, b = lane & 15;
        acc = __builtin_amdgcn_mfma_f32_16x16x32_bf16(*(const bf16x8*)&Hrow[d][b][ks * 32 + ch * 8],
                                                      *(const bf16x8*)Wt[d][(ks * 4 + ch) * 16 + b],
                                                      acc, 0, 0, 0);
      }
      P[d][wv][lane] = acc;
    }
    __syncthreads();
    if (wv < 2){
      int d = wv;
      f32x4 sum = (P[d][0][lane] + P[d][1][lane]) + (P[d][2][lane] + P[d][3][lane]);
      int v = lane & 15;
      int n = (v & 3) * 512 + bx * 4 + (v >> 2);
      int s_in = d ? (127 - t) : t;
      const float* gg = (d ? gin_b : gin_f) + (size_t)s_in * 16 * 2048 + n;
      #pragma unroll
      for (int r = 0; r < 4; r++){
        int b = (lane >> 4) * 4 + r;
        gl[d][v][b] = sum[r] + gg[(size_t)b * 2048];
      }
    }
    __syncthreads();
    if (tid < 128){
      float ig = sigm (gl[cd][cj * 4 + 0][cb]);
      float fg = sigm (gl[cd][cj * 4 + 1][cb]);
      float g2 = tanhf(gl[cd][cj * 4 + 2][cb]);
      float og = sigm (gl[cd][cj * 4 + 3][cb]);
      float cn = fg * creg + ig * g2;
      float hv = og * tanhf(cn);
      creg = cn;
      hvout[cd][cb][cj] = hv;
    }
    __syncthreads();
    if (tid < 64){
      int d = tid >> 5, rem = tid & 31, b = rem & 15, jp = rem >> 4;
      int s_in = d ? (127 - t) : t;
      st4v((unsigned*)(enc_out_bf + ((size_t)b * 128 + s_in) * 1024 + d * 512 + bx * 4 + jp * 2),
           pack2(f2bf(hvout[d][b][jp * 2]), f2bf(hvout[d][b][jp * 2 + 1])));
    }
    if (t != 127) gridbar3(arr, t + 1);
  }
}

// ---------------- h0/c0 ----------------
__global__ __launch_bounds__(512)
void k_h0c0(const us* __restrict__ enc_out_bf, const float* __restrict__ Wbh, const float* __restrict__ bbh,
            const float* __restrict__ Wbc, const float* __restrict__ bbc,
            us* __restrict__ h0_bf, float* __restrict__ c_dec)
{
  __shared__ float hc[1024];
  int b = blockIdx.x >> 1, which = blockIdx.x & 1;
  int tid = threadIdx.x;
  hc[tid]       = bf2f(enc_out_bf[((size_t)b * 128 + 127) * 1024 + tid]);
  hc[512 + tid] = bf2f(enc_out_bf[((size_t)b * 128 + 0)   * 1024 + 512 + tid]);
  __syncthreads();
  const float* W = which ? Wbc : Wbh;
  float acc = (which ? bbc : bbh)[tid];
  const float* wr = W + (size_t)tid * 1024;
  for (int k = 0; k < 1024; k += 4){
    float4 w = *(const float4*)(wr + k);
    acc += w.x * hc[k] + w.y * hc[k + 1] + w.z * hc[k + 2] + w.w * hc[k + 3];
  }
  float v = tanhf(acc);
  if (which) c_dec[b * 512 + tid] = v;
  else       h0_bf[b * 512 + tid] = f2bf(v);
}

// =================================================================================
// Persistent decoder v6: fence-free, 4 barriers/step. All cross-block exchange via
// sc1 atomics; staging is coalesced 8B loads into padded row-major LDS.
// =================================================================================
__global__ __launch_bounds__(256)
void dec_persist6(const us* __restrict__ h0_bf, const float* __restrict__ c_dec0,
                  const float* __restrict__ Ws_att, const float* __restrict__ v_att,
                  const us* __restrict__ enc_proj_bf,
                  const us* __restrict__ enc_out_bf,
                  const int* __restrict__ src_lens,
                  const float* __restrict__ gin_d,
                  const us* __restrict__ whhd_bf, const us* __restrict__ wihd_bf,
                  float* __restrict__ hs_g, float* __restrict__ scores_g,
                  us* __restrict__ hctx,
                  unsigned* __restrict__ arr)
{
  __shared__ __align__(16) us Wh[1024][8];     // 16KB resident (A)
  __shared__ __align__(16) us Wc[2048][8];     // 32KB resident (D)
  __shared__ __align__(16) us Ws_r[4][512];    // 4KB resident (A)
  __shared__ __align__(16) us ep_r[16][512];   // 16KB resident (B)
  __shared__ __align__(16) us eo_r[128][128];  // 32KB resident (C)
  __shared__ __align__(16) us Xrow[16][1032];  // 33KB padded row-major x (A: h, D: ctx)
  __shared__ __align__(16) f32x4 P[4][64];     // 4KB
  __shared__ float g1l[16][17];
  __shared__ float gl[16][17];
  __shared__ float vl[512];
  __shared__ float hsp[4][64];
  __shared__ float hs_b[512];
  __shared__ float att[128];
  __shared__ float cred[2][128];
  __shared__ float sred[8];
  __shared__ float hvs[16][4];

  const int bx = blockIdx.x, tid = threadIdx.x;
  const int lane = tid & 63, wv = tid >> 6;
  const int bB = bx & 15, sQ = bx >> 4;

  // ---- resident loads (once, normal cached — kernel-boundary fresh) ----
  for (int u = tid; u < 1024; u += 256){
    int ks = u >> 6, ch = (u >> 4) & 3, v = u & 15;
    int n = (v & 3) * 512 + bx * 4 + (v >> 2);
    *(bf16x8*)Wh[u] = *(const bf16x8*)(whhd_bf + (size_t)n * 512 + ks * 32 + ch * 8);
  }
  for (int u = tid; u < 2048; u += 256){
    int ks = u >> 6, ch = (u >> 4) & 3, v = u & 15;
    int n = (v & 3) * 512 + bx * 4 + (v >> 2);
    *(bf16x8*)Wc[u] = *(const bf16x8*)(wihd_bf + (size_t)n * 1536 + 512 + ks * 32 + ch * 8);
  }
  for (int u = tid; u < 2048; u += 256){
    int a = u >> 9, k = u & 511;
    Ws_r[a][k] = f2bf(Ws_att[(size_t)(bx * 4 + a) * 512 + k]);
  }
  for (int u = tid; u < 1024; u += 256){      // ep_r: s = sQ*16+si
    int si = u >> 6, a8 = (u & 63) * 8;
    *(bf16x8*)&ep_r[si][a8] =
      *(const bf16x8*)(enc_proj_bf + ((size_t)bB * 128 + sQ * 16 + si) * 512 + a8);
  }
  for (int u = tid; u < 2048; u += 256){      // eo_r: k = sQ*128+kk
    int s = u >> 4, k8 = (u & 15) * 8;
    *(bf16x8*)&eo_r[s][k8] =
      *(const bf16x8*)(enc_out_bf + ((size_t)bB * 128 + s) * 1024 + sQ * 128 + k8);
  }
  for (int u = tid; u < 512; u += 256) vl[u] = v_att[u];
  const int slen = src_lens[bB];

  float creg = 0.0f;                 // tid<64 owns (b=tid&15, j=bx*4+(tid>>4))
  if (tid < 64) creg = c_dec0[(tid & 15) * 512 + bx * 4 + (tid >> 4)];

  for (int t = 0; t < 127; t++){
    const us* hsrc = t ? (hctx + (size_t)(t - 1) * 16 * 1536) : h0_bf;
    const int hstride = t ? 1536 : 512;

    // ====== phase A: stage h (sc1 coalesced); h@Whh -> g1l ; hs slice -> hs_g ======
    #pragma unroll
    for (int r = 0; r < 4; r++){
      int u = tid + r * 256;                  // u = b*64 + s16
      int b = u >> 6, s16 = u & 63;
      const us* s = hsrc + (size_t)b * hstride + s16 * 8;
      ull lo = ld8v(s), hi = ld8v(s + 4);
      *(ull*)&Xrow[b][s16 * 8]     = lo;
      *(ull*)&Xrow[b][s16 * 8 + 4] = hi;
    }
    __syncthreads();
    {
      f32x4 acc = {};
      #pragma unroll
      for (int m = 0; m < 4; m++){
        int ks = wv * 4 + m;
        int ch = lane >> 4, b = lane & 15;
        acc = __builtin_amdgcn_mfma_f32_16x16x32_bf16(*(const bf16x8*)&Xrow[b][ks * 32 + ch * 8],
                                                      *(const bf16x8*)Wh[(ks * 4 + ch) * 16 + b],
                                                      acc, 0, 0, 0);
      }
      P[wv][lane] = acc;
    }
    {  // hs partials: a-rows bx*4..+3, vectorized LDS reads
      int pr = tid & 63, bq = pr & 15, ai = pr >> 4, kq = wv;
      const us* wr = Ws_r[ai] + kq * 128;
      const us* xr = Xrow[bq] + kq * 128;
      float s = 0.f;
      #pragma unroll
      for (int k = 0; k < 128; k += 8){
        bf16x8 xv = *(const bf16x8*)(xr + k);
        bf16x8 wv8 = *(const bf16x8*)(wr + k);
        #pragma unroll
        for (int e = 0; e < 8; e++) s += (float)xv[e] * (float)wv8[e];
      }
      hsp[kq][pr] = s;
    }
    __syncthreads();
    if (wv == 0){
      f32x4 sum = (P[0][lane] + P[1][lane]) + (P[2][lane] + P[3][lane]);
      int v = lane & 15;
      int n = (v & 3) * 512 + bx * 4 + (v >> 2);
      #pragma unroll
      for (int r = 0; r < 4; r++){
        int b = (lane >> 4) * 4 + r;
        g1l[v][b] = sum[r] + gin_d[((size_t)t * 16 + b) * 2048 + n];
      }
    }
    if (tid < 64){
      float v = hsp[0][tid] + hsp[1][tid] + hsp[2][tid] + hsp[3][tid];
      st4v((unsigned*)&hs_g[(tid & 15) * 512 + bx * 4 + (tid >> 4)], __float_as_uint(v));
    }

    gridbar3(arr, 4 * t + 1);

    // ====== phase B: scores[bB][sQ*16..+15] ======
    {
      ull v = ld8v(&hs_g[bB * 512 + tid * 2]);
      *(ull*)&hs_b[tid * 2] = v;
    }
    __syncthreads();
    {
      int si = tid >> 4, part = tid & 15;     // a-range part*32..+31
      const us* er = ep_r[si] + part * 32;
      const float* hb = hs_b + part * 32;
      const float* vp = vl + part * 32;
      float sv = 0.f;
      #pragma unroll
      for (int a = 0; a < 32; a += 8){
        uint4 u4 = *(const uint4*)(er + a);
        float e0,e1,e2,e3,e4,e5,e6,e7;
        unpk2(u4.x,e0,e1); unpk2(u4.y,e2,e3); unpk2(u4.z,e4,e5); unpk2(u4.w,e6,e7);
        sv += vp[a+0]*tanh_fast(e0+hb[a+0]) + vp[a+1]*tanh_fast(e1+hb[a+1])
            + vp[a+2]*tanh_fast(e2+hb[a+2]) + vp[a+3]*tanh_fast(e3+hb[a+3])
            + vp[a+4]*tanh_fast(e4+hb[a+4]) + vp[a+5]*tanh_fast(e5+hb[a+5])
            + vp[a+6]*tanh_fast(e6+hb[a+6]) + vp[a+7]*tanh_fast(e7+hb[a+7]);
      }
      sv += __shfl_xor(sv, 1);
      sv += __shfl_xor(sv, 2);
      sv += __shfl_xor(sv, 4);
      sv += __shfl_xor(sv, 8);
      if (part == 0){
        int s = sQ * 16 + si;
        st4v((unsigned*)&scores_g[bB * 128 + s], __float_as_uint((s < slen) ? sv : -1e9f));
      }
    }

    gridbar3(arr, 4 * t + 2);

    // ====== phase C: softmax(bB) + ctx[bB][sQ*128..+127] ======
    {
      float x = (tid < 128) ? __uint_as_float(ld4v((unsigned*)&scores_g[bB * 128 + tid])) : -3e38f;
      float m = x;
      #pragma unroll
      for (int o = 32; o; o >>= 1) m = fmaxf(m, __shfl_xor(m, o));
      if (lane == 0) sred[wv] = m;
      __syncthreads();
      m = fmaxf(fmaxf(sred[0], sred[1]), fmaxf(sred[2], sred[3]));
      float e = (tid < 128) ? __expf(x - m) : 0.f;
      float ss = e;
      #pragma unroll
      for (int o = 32; o; o >>= 1) ss += __shfl_xor(ss, o);
      if (lane == 0) sred[4 + wv] = ss;
      __syncthreads();
      float inv = 1.0f / (sred[4] + sred[5] + sred[6] + sred[7]);
      if (tid < 128) att[tid] = e * inv;
    }
    __syncthreads();
    {
      int kk = tid & 127, half = tid >> 7;
      const float* ab = att + half * 64;
      const us* er = &eo_r[half * 64][kk];
      float s = 0.f;
      #pragma unroll 8
      for (int s2 = 0; s2 < 64; s2++)
        s += ab[s2] * bf2f(er[(size_t)s2 * 128]);
      cred[half][kk] = s;
    }
    __syncthreads();
    if (tid < 64){
      int kk2 = tid * 2;
      float c0 = cred[0][kk2]     + cred[1][kk2];
      float c1 = cred[0][kk2 + 1] + cred[1][kk2 + 1];
      st4v((unsigned*)(hctx + ((size_t)t * 16 + bB) * 1536 + 512 + sQ * 128 + kk2),
           pack2(f2bf(c0), f2bf(c1)));
    }

    gridbar3(arr, 4 * t + 3);

    // ====== phase D: stage ctx (sc1 coalesced); ctx@Wc + g1l -> gates -> cell ======
    #pragma unroll
    for (int r = 0; r < 8; r++){
      int u = tid + r * 256;                  // u = b*128 + s16
      int b = u >> 7, s16 = u & 127;
      const us* s = hctx + ((size_t)t * 16 + b) * 1536 + 512 + s16 * 8;
      ull lo = ld8v(s), hi = ld8v(s + 4);
      *(ull*)&Xrow[b][s16 * 8]     = lo;
      *(ull*)&Xrow[b][s16 * 8 + 4] = hi;
    }
    __syncthreads();
    {
      f32x4 acc = {};
      #pragma unroll
      for (int m = 0; m < 8; m++){
        int ks = wv * 8 + m;
        int ch = lane >> 4, b = lane & 15;
        acc = __builtin_amdgcn_mfma_f32_16x16x32_bf16(*(const bf16x8*)&Xrow[b][ks * 32 + ch * 8],
                                                      *(const bf16x8*)Wc[(ks * 4 + ch) * 16 + b],
                                                      acc, 0, 0, 0);
      }
      P[wv][lane] = acc;
    }
    __syncthreads();
    if (wv == 0){
      f32x4 sum = (P[0][lane] + P[1][lane]) + (P[2][lane] + P[3][lane]);
      int v = lane & 15;
      #pragma unroll
      for (int r = 0; r < 4; r++){
        int b = (lane >> 4) * 4 + r;
        gl[v][b] = sum[r] + g1l[v][b];
      }
    }
    __syncthreads();
    if (tid < 64){
      int b2 = tid & 15, joff = tid >> 4;
      float ig = sigm (gl[joff * 4 + 0][b2]);
      float fg = sigm (gl[joff * 4 + 1][b2]);
      float g2 = tanhf(gl[joff * 4 + 2][b2]);
      float og = sigm (gl[joff * 4 + 3][b2]);
      float cn = fg * creg + ig * g2;
      float hv = og * tanhf(cn);
      creg = cn;
      hvs[b2][joff] = hv;
    }
    __syncthreads();
    if (tid < 32){
      int b = tid & 15, jp = tid >> 4;
      st4v((unsigned*)(hctx + ((size_t)t * 16 + b) * 1536 + bx * 4 + jp * 2),
           pack2(f2bf(hvs[b][jp * 2]), f2bf(hvs[b][jp * 2 + 1])));
    }
    if (t != 126) gridbar3(arr, 4 * t + 4);
  }
}

extern "C" void kernel_launch(void* const* d_in, const int* in_sizes, int n_in,
                              void* d_out, int out_size, void* d_ws, size_t ws_size,
                              hipStream_t stream)
{
  const int*   src       = (const int*)d_in[0];
  const int*   src_lens  = (const int*)d_in[1];
  const int*   tgt       = (const int*)d_in[2];
  const float* enc_embed = (const float*)d_in[3];
  const float* Wih_f = (const float*)d_in[4];
  const float* Whh_f = (const float*)d_in[5];
  const float* bih_f = (const float*)d_in[6];
  const float* bhh_f = (const float*)d_in[7];
  const float* Wih_b = (const float*)d_in[8];
  const float* Whh_b = (const float*)d_in[9];
  const float* bih_b = (const float*)d_in[10];
  const float* bhh_b = (const float*)d_in[11];
  const float* Wbh = (const float*)d_in[12];
  const float* bbh = (const float*)d_in[13];
  const float* Wbc = (const float*)d_in[14];
  const float* bbc = (const float*)d_in[15];
  const float* Wh_att = (const float*)d_in[16];
  const float* Ws_att = (const float*)d_in[17];
  const float* v_att  = (const float*)d_in[18];
  const float* dec_embed = (const float*)d_in[19];
  const float* Wih_d = (const float*)d_in[20];
  const float* Whh_d = (const float*)d_in[21];
  const float* bih_d = (const float*)d_in[22];
  const float* bhh_d = (const float*)d_in[23];
  const float* Wfc = (const float*)d_in[24];
  const float* bfc = (const float*)d_in[25];
  float* out = (float*)d_out;

  char* base = (char*)d_ws;
  size_t off = 0;
  auto take = [&](size_t bytes) -> char* {
    char* p = base + off;
    off += (bytes + 255) & ~(size_t)255;
    return p;
  };
  us* wfc_bf    = (us*)take((size_t)32000 * 1536 * 2);
  us* emb_e     = (us*)take((size_t)2048 * 512 * 2);
  us* emb_d     = (us*)take((size_t)2048 * 512 * 2);
  us* wihf_bf   = (us*)take((size_t)2048 * 512 * 2);
  us* wihb_bf   = (us*)take((size_t)2048 * 512 * 2);
  us* wihd_bf   = (us*)take((size_t)2048 * 1536 * 2);
  us* whhf_bf   = (us*)take((size_t)2048 * 512 * 2);
  us* whhb_bf   = (us*)take((size_t)2048 * 512 * 2);
  us* whhd_bf   = (us*)take((size_t)2048 * 512 * 2);
  us* whatt_bf  = (us*)take((size_t)512 * 1024 * 2);
  float* gin_f    = (float*)take((size_t)2048 * 2048 * 4);
  float* gin_b    = (float*)take((size_t)2048 * 2048 * 4);
  float* gin_d    = (float*)take((size_t)2048 * 2048 * 4);
  us* enc_out_bf  = (us*)take((size_t)2048 * 1024 * 2);
  us* enc_proj_bf = (us*)take((size_t)2048 * 512 * 2);
  us* hctx        = (us*)take((size_t)2048 * 1536 * 2);
  us* h0_bf       = (us*)take((size_t)16 * 512 * 2);
  float* c_dec    = (float*)take((size_t)16 * 512 * 4);
  float* hs_g     = (float*)take((size_t)16 * 512 * 4);
  float* scores_g = (float*)take((size_t)2048 * 4);
  float* bias_f = (float*)take(2048 * 4);
  float* bias_b = (float*)take(2048 * 4);
  float* bias_d = (float*)take(2048 * 4);
  unsigned* arrE = (unsigned*)take(128 * 16 * 4);
  unsigned* arrD = (unsigned*)take(128 * 16 * 4);

  // zeroing: padded dec-embedding rows, hctx (incl. padded logit rows), barrier flags
  hipMemsetAsync(emb_d, 0, (size_t)2048 * 512 * 2, stream);
  hipMemsetAsync(hctx, 0, (size_t)2048 * 1536 * 2, stream);
  hipMemsetAsync(arrE, 0, (128 * 16 + 128 * 16) * 4 + 256, stream);

  // weight conversions
  k_f2bf<<<4096, 256, 0, stream>>>((const float4*)Wfc,   (uint2*)wfc_bf,   (long)32000 * 1536 / 4);
  k_f2bf<<<512,  256, 0, stream>>>((const float4*)Wih_f, (uint2*)wihf_bf,  (long)2048 * 512 / 4);
  k_f2bf<<<512,  256, 0, stream>>>((const float4*)Wih_b, (uint2*)wihb_bf,  (long)2048 * 512 / 4);
  k_f2bf<<<1024, 256, 0, stream>>>((const float4*)Wih_d, (uint2*)wihd_bf,  (long)2048 * 1536 / 4);
  k_f2bf<<<512,  256, 0, stream>>>((const float4*)Whh_f, (uint2*)whhf_bf,  (long)2048 * 512 / 4);
  k_f2bf<<<512,  256, 0, stream>>>((const float4*)Whh_b, (uint2*)whhb_bf,  (long)2048 * 512 / 4);
  k_f2bf<<<512,  256, 0, stream>>>((const float4*)Whh_d, (uint2*)whhd_bf,  (long)2048 * 512 / 4);
  k_f2bf<<<512,  256, 0, stream>>>((const float4*)Wh_att,(uint2*)whatt_bf, (long)512 * 1024 / 4);
  k_bias3<<<8, 256, 0, stream>>>(bih_f, bhh_f, bias_f, bih_b, bhh_b, bias_b, bih_d, bhh_d, bias_d);

  // embeddings (bf16), rows r = pos*16 + b
  k_embed<<<2048, 128, 0, stream>>>(src, enc_embed, emb_e);
  k_embed<<<2032, 128, 0, stream>>>(tgt, dec_embed, emb_d);

  // input-side gate GEMMs (hoisted out of the scans)
  gemm_bt<0><<<dim3(16, 16), 256, 0, stream>>>(emb_e, 512, wihf_bf, 512,  bias_f, gin_f, 2048, 512, 4096);
  gemm_bt<0><<<dim3(16, 16), 256, 0, stream>>>(emb_e, 512, wihb_bf, 512,  bias_b, gin_b, 2048, 512, 4096);
  gemm_bt<0><<<dim3(16, 16), 256, 0, stream>>>(emb_d, 512, wihd_bf, 1536, bias_d, gin_d, 2048, 512, 4096);

  // encoder: persistent, fence-free barriers
  enc_persist4<<<128, 256, 0, stream>>>(gin_f, gin_b, whhf_bf, whhb_bf, enc_out_bf, arrE);

  k_h0c0<<<32, 512, 0, stream>>>(enc_out_bf, Wbh, bbh, Wbc, bbc, h0_bf, c_dec);

  // enc_proj (bf16) = enc_out @ Wh_att^T
  gemm_bt<2><<<dim3(4, 16), 256, 0, stream>>>(enc_out_bf, 1024, whatt_bf, 1024, nullptr, enc_proj_bf, 512, 1024, 4096);

  // decoder: persistent, fence-free barriers, sc1 exchange
  dec_persist6<<<128, 256, 0, stream>>>(h0_bf, c_dec, Ws_att, v_att, enc_proj_bf, enc_out_bf, src_lens,
                                        gin_d, whhd_bf, wihd_bf, hs_g, scores_g, hctx, arrD);

  // one big logits GEMM: [2032,1536] x [32000,1536]^T + bfc -> out (B,T-1,V)
  gemm_bt<1><<<dim3(250, 16), 256, 0, stream>>>(hctx, 1536, wfc_bf, 1536, bfc, out, 32000, 1536, 2032);
}